// Round 1
// baseline (622.245 us; speedup 1.0000x reference)
//
#include <hip/hip_runtime.h>
#include <math.h>

#define NB 66                       // segments 0..65
#define PAD(f) ((f) + ((f) >> 4))   // LDS padding: +1 complex every 16

typedef float2 cplx;

__device__ __forceinline__ cplx cmul(cplx a, cplx b) {
    return make_float2(a.x * b.x - a.y * b.y, a.x * b.y + a.y * b.x);
}

__device__ __forceinline__ int rev4(int j) {
    // base-4 digit reversal of an 8-bit index
    return ((j & 3) << 6) | (((j >> 2) & 3) << 4) | (((j >> 4) & 3) << 2) | ((j >> 6) & 3);
}

// In-place radix-4 DIT 256-pt FFT in padded LDS buffer (one wave per buffer).
// Input must be written digit-reversed: buf[PAD(rev4(j))] = x[j]. Output natural order.
// Contains __syncthreads -> must be called uniformly by all threads of the block.
__device__ void fft256(cplx* buf, int lane, const cplx* tw) {
    #pragma unroll
    for (int s = 0; s < 4; ++s) {
        const int qsh = 2 * s;
        const int quarter = 1 << qsh;
        const int p = lane & (quarter - 1);
        const int g = lane >> qsh;
        const int base = (g << (qsh + 2)) + p;
        const int e = p << (6 - qsh);         // p * (256/L), L = 4*quarter
        __syncthreads();
        cplx t0 = buf[PAD(base)];
        cplx t1 = buf[PAD(base + quarter)];
        cplx t2 = buf[PAD(base + 2 * quarter)];
        cplx t3 = buf[PAD(base + 3 * quarter)];
        t1 = cmul(t1, tw[e]);
        t2 = cmul(t2, tw[2 * e]);
        t3 = cmul(t3, tw[3 * e]);
        cplx a = make_float2(t0.x + t2.x, t0.y + t2.y);
        cplx b = make_float2(t0.x - t2.x, t0.y - t2.y);
        cplx c = make_float2(t1.x + t3.x, t1.y + t3.y);
        cplx d = make_float2(t1.x - t3.x, t1.y - t3.y);
        // wave-wide: all 64 lanes' reads issue before writes; DS pipe is in-order,
        // and same-buffer aliasing prevents compiler store/load reordering.
        buf[PAD(base)]               = make_float2(a.x + c.x, a.y + c.y);
        buf[PAD(base + quarter)]     = make_float2(b.x + d.y, b.y - d.x);  // b + (-i)d
        buf[PAD(base + 2 * quarter)] = make_float2(a.x - c.x, a.y - c.y);
        buf[PAD(base + 3 * quarter)] = make_float2(b.x - d.y, b.y + d.x);  // b + (i)d
    }
    __syncthreads();
}

// Pass 1: row FFTs of real input; keep kx = 0..128 (Hermitian half), write
// transposed intermediate inter[img][kx][y] (y contiguous) via an LDS tile.
__global__ __launch_bounds__(256) void k_rowfft(const float* __restrict__ pred,
                                                cplx* __restrict__ inter) {
    __shared__ cplx tw[256];
    __shared__ cplx rowbuf[4][272];
    __shared__ cplx tile[129][33];   // [kx][row-in-slab], padded
    const int tid = threadIdx.x, w = tid >> 6, lane = tid & 63;
    const int img = blockIdx.x >> 3, slab = blockIdx.x & 7;
    const int y0 = slab * 32;

    {
        float sg, cg;
        __sincosf(-6.283185307179586f * (float)tid / 256.0f, &sg, &cg);
        tw[tid] = make_float2(cg, sg);
    }
    __syncthreads();

    for (int i = 0; i < 8; ++i) {
        const int rr = w * 8 + i;                 // row within slab
        const int y = y0 + rr;
        const float* src = pred + ((size_t)img * 256 + y) * 256;
        #pragma unroll
        for (int q = 0; q < 4; ++q) {
            const int j = lane + 64 * q;
            rowbuf[w][PAD(rev4(j))] = make_float2(src[j], 0.0f);
        }
        fft256(rowbuf[w], lane, tw);
        #pragma unroll
        for (int q = 0; q < 3; ++q) {
            const int kx = lane + 64 * q;
            if (kx < 129) tile[kx][rr] = rowbuf[w][PAD(kx)];
        }
    }
    __syncthreads();
    for (int idx = tid; idx < 129 * 32; idx += 256) {
        const int kx = idx >> 5, yy = idx & 31;
        inter[((size_t)img * 129 + kx) * 256 + (y0 + yy)] = tile[kx][yy];
    }
}

// Pass 2: per image, column FFTs for kx=0..128, |F|^2 with symmetry weight,
// radial binning in LDS, then the per-image weighted log-MSE contribution.
__global__ __launch_bounds__(512) void k_colfft(const cplx* __restrict__ inter,
                                                const int* __restrict__ seg,
                                                const float* __restrict__ invcnt,
                                                const float* __restrict__ mean_cl,
                                                const float* __restrict__ weighting,
                                                float* __restrict__ out,
                                                float cscale, float invBN) {
    __shared__ cplx tw[256];
    __shared__ cplx rowbuf[8][272];
    __shared__ float bins[NB];
    const int tid = threadIdx.x, w = tid >> 6, lane = tid & 63;
    const int img = blockIdx.x;

    if (tid < 256) {
        float sg, cg;
        __sincosf(-6.283185307179586f * (float)tid / 256.0f, &sg, &cg);
        tw[tid] = make_float2(cg, sg);
    }
    if (tid < NB) bins[tid] = 0.0f;
    __syncthreads();

    for (int it = 0; it < 17; ++it) {            // 8 waves x 17 >= 129 columns
        const int kx = w + 8 * it;
        const bool act = (kx < 129);
        if (act) {
            const cplx* src = inter + ((size_t)img * 129 + kx) * 256;
            #pragma unroll
            for (int q = 0; q < 4; ++q) {
                const int j = lane + 64 * q;
                rowbuf[w][PAD(rev4(j))] = src[j];
            }
        }
        fft256(rowbuf[w], lane, tw);             // uniform barriers for all waves
        if (act) {
            const float symw = (kx == 0 || kx == 128) ? 1.0f : 2.0f;
            #pragma unroll
            for (int q = 0; q < 4; ++q) {
                const int ky = lane + 64 * q;
                const cplx v = rowbuf[w][PAD(ky)];
                const float P = (v.x * v.x + v.y * v.y) * symw;
                // seg is symmetric: seg[ky*256+kx] == seg[kx*256+ky]; use coalesced form
                const int s = seg[kx * 256 + ky];
                atomicAdd(&bins[s], P);
            }
        }
    }
    __syncthreads();

    if (tid < 64) {
        const int b = tid + 1;                    // valid segments 1..64
        const float v = bins[b] * cscale * invcnt[b];
        const float diff = logf(v + 1e-12f) - logf(mean_cl[tid] + 1e-12f);
        float acc = weighting[tid] * diff * diff;
        #pragma unroll
        for (int o = 32; o; o >>= 1) acc += __shfl_down(acc, o);
        if (tid == 0) atomicAdd(out, acc * invBN);
    }
}

__global__ void k_counts(const int* __restrict__ seg, float* __restrict__ invcnt, int n) {
    __shared__ int cnt[NB];
    const int tid = threadIdx.x;
    if (tid < NB) cnt[tid] = 0;
    __syncthreads();
    for (int i = tid; i < n; i += blockDim.x) atomicAdd(&cnt[seg[i]], 1);
    __syncthreads();
    if (tid < NB) invcnt[tid] = cnt[tid] > 0 ? 1.0f / (float)cnt[tid] : 0.0f;
}

extern "C" void kernel_launch(void* const* d_in, const int* in_sizes, int n_in,
                              void* d_out, int out_size, void* d_ws, size_t ws_size,
                              hipStream_t stream) {
    const float* pred      = (const float*)d_in[0];
    const float* mean_cl   = (const float*)d_in[1];
    const float* weighting = (const float*)d_in[2];
    const int*   seg       = (const int*)d_in[3];
    float* out = (float*)d_out;

    const int B = in_sizes[0] / 65536;

    float* invcnt = (float*)d_ws;                          // 66 floats
    cplx*  inter  = (cplx*)((char*)d_ws + 1024);
    const size_t per_img = (size_t)129 * 256 * sizeof(cplx);   // 264192 B
    const size_t avail = ws_size > 1024 ? ws_size - 1024 : 0;
    int chunk = (int)(avail / per_img);
    if (chunk > B) chunk = B;
    if (chunk < 1) chunk = 1;

    const double rad = (5.0 * 60.0 / 256.0) * M_PI / 180.0;
    const float cscale = (float)(rad * rad / (65536.0 * 1e12)); // rad^2/N^2 / TSZ^2
    const float invBN  = (float)(1.0 / ((double)B * 64.0));

    hipMemsetAsync(d_out, 0, sizeof(float), stream);
    k_counts<<<1, 256, 0, stream>>>(seg, invcnt, in_sizes[3]);

    for (int b0 = 0; b0 < B; b0 += chunk) {
        const int cb = (B - b0) < chunk ? (B - b0) : chunk;
        k_rowfft<<<cb * 8, 256, 0, stream>>>(pred + (size_t)b0 * 65536, inter);
        k_colfft<<<cb, 512, 0, stream>>>(inter, seg, invcnt, mean_cl, weighting,
                                         out, cscale, invBN);
    }
}

// Round 2
// 519.310 us; speedup vs baseline: 1.1982x; 1.1982x over previous
//
#include <hip/hip_runtime.h>
#include <math.h>

#define NB 66                       // segments 0..65
#define PAD(f) ((f) + ((f) >> 4))   // LDS padding: +1 complex every 16

typedef float2 cplx;

__device__ __forceinline__ cplx cmul(cplx a, cplx b) {
    return make_float2(a.x * b.x - a.y * b.y, a.x * b.y + a.y * b.x);
}

__device__ __forceinline__ int rev4(int j) {
    // base-4 digit reversal of an 8-bit index
    return ((j & 3) << 6) | (((j >> 2) & 3) << 4) | (((j >> 4) & 3) << 2) | ((j >> 6) & 3);
}

// In-place radix-4 DIT 256-pt FFT in padded LDS buffer, ONE WAVE per buffer.
// Wave-synchronous: LDS ops from a single wave execute in order on the DS
// pipe, and the compiler cannot hoist the stage-s+1 loads above the stage-s
// stores (same base pointer, runtime indices -> must-alias). No barriers.
// Input written digit-reversed: buf[PAD(rev4(j))] = x[j]. Output natural order.
__device__ void fft256(cplx* buf, int lane, const cplx* tw) {
    #pragma unroll
    for (int s = 0; s < 4; ++s) {
        const int qsh = 2 * s;
        const int quarter = 1 << qsh;
        const int p = lane & (quarter - 1);
        const int g = lane >> qsh;
        const int base = (g << (qsh + 2)) + p;
        const int e = p << (6 - qsh);         // p * (256/L), L = 4*quarter
        cplx t0 = buf[PAD(base)];
        cplx t1 = buf[PAD(base + quarter)];
        cplx t2 = buf[PAD(base + 2 * quarter)];
        cplx t3 = buf[PAD(base + 3 * quarter)];
        t1 = cmul(t1, tw[e]);
        t2 = cmul(t2, tw[2 * e]);
        t3 = cmul(t3, tw[3 * e]);
        cplx a = make_float2(t0.x + t2.x, t0.y + t2.y);
        cplx b = make_float2(t0.x - t2.x, t0.y - t2.y);
        cplx c = make_float2(t1.x + t3.x, t1.y + t3.y);
        cplx d = make_float2(t1.x - t3.x, t1.y - t3.y);
        buf[PAD(base)]               = make_float2(a.x + c.x, a.y + c.y);
        buf[PAD(base + quarter)]     = make_float2(b.x + d.y, b.y - d.x);  // b + (-i)d
        buf[PAD(base + 2 * quarter)] = make_float2(a.x - c.x, a.y - c.y);
        buf[PAD(base + 3 * quarter)] = make_float2(b.x - d.y, b.y + d.x);  // b + (i)d
    }
}

// Pass 1: row FFTs of real input, 8-row slabs; keep kx = 0..128 (Hermitian
// half), write transposed intermediate inter[img][kx][y] via padded LDS tile.
__global__ __launch_bounds__(256) void k_rowfft(const float* __restrict__ pred,
                                                cplx* __restrict__ inter) {
    __shared__ cplx tw[256];
    __shared__ cplx rowbuf[4][272];
    __shared__ cplx tile[129][9];    // [kx][row-in-slab], odd pad
    const int tid = threadIdx.x, w = tid >> 6, lane = tid & 63;
    const int img = blockIdx.x >> 5, slab = blockIdx.x & 31;
    const int y0 = slab * 8;

    {
        float sg, cg;
        __sincosf(-6.283185307179586f * (float)tid / 256.0f, &sg, &cg);
        tw[tid] = make_float2(cg, sg);
    }
    __syncthreads();

    #pragma unroll
    for (int i = 0; i < 2; ++i) {
        const int rr = w * 2 + i;                 // row within slab
        const float* src = pred + ((size_t)img * 256 + y0 + rr) * 256;
        #pragma unroll
        for (int q = 0; q < 4; ++q) {
            const int j = lane + 64 * q;
            rowbuf[w][PAD(rev4(j))] = make_float2(src[j], 0.0f);
        }
        fft256(rowbuf[w], lane, tw);              // wave-local, no barriers
        #pragma unroll
        for (int q = 0; q < 3; ++q) {
            const int kx = lane + 64 * q;
            if (kx < 129) tile[kx][rr] = rowbuf[w][PAD(kx)];
        }
    }
    __syncthreads();
    for (int idx = tid; idx < 129 * 8; idx += 256) {
        const int kx = idx >> 3, yy = idx & 7;
        inter[((size_t)img * 129 + kx) * 256 + (y0 + yy)] = tile[kx][yy];
    }
}

// Pass 2: column FFTs, 8 columns per block (2 serial FFTs per wave),
// |F|^2 with Hermitian symmetry weight, per-WAVE bin accumulation in LDS,
// then per-image global bin accumulation in ws.
__global__ __launch_bounds__(256) void k_colfft(const cplx* __restrict__ inter,
                                                const int* __restrict__ seg,
                                                float* __restrict__ imgbins) {
    __shared__ cplx tw[256];
    __shared__ cplx rowbuf[4][272];
    __shared__ float bins[4][NB];
    const int tid = threadIdx.x, w = tid >> 6, lane = tid & 63;
    const int img = blockIdx.x / 17, slab = blockIdx.x % 17;

    {
        float sg, cg;
        __sincosf(-6.283185307179586f * (float)tid / 256.0f, &sg, &cg);
        tw[tid] = make_float2(cg, sg);
    }
    for (int i = lane; i < NB; i += 64) bins[w][i] = 0.0f;
    __syncthreads();   // tw visible to all waves

    #pragma unroll
    for (int c = 0; c < 2; ++c) {
        const int kx = slab * 8 + w * 2 + c;
        if (kx < 129) {
            const cplx* src = inter + ((size_t)img * 129 + kx) * 256;
            #pragma unroll
            for (int q = 0; q < 4; ++q) {
                const int j = lane + 64 * q;
                rowbuf[w][PAD(rev4(j))] = src[j];
            }
            fft256(rowbuf[w], lane, tw);          // wave-local, no barriers
            const float symw = (kx == 0 || kx == 128) ? 1.0f : 2.0f;
            #pragma unroll
            for (int q = 0; q < 4; ++q) {
                const int ky = lane + 64 * q;
                const cplx v = rowbuf[w][PAD(ky)];
                const float P = (v.x * v.x + v.y * v.y) * symw;
                // seg symmetric: seg[ky*256+kx] == seg[kx*256+ky]; coalesced form
                const int s = seg[kx * 256 + ky];
                atomicAdd(&bins[w][s], P);
            }
        }
    }
    __syncthreads();

    if (tid < 64) {                               // valid segments 1..64
        const int s = tid + 1;
        const float sum = bins[0][s] + bins[1][s] + bins[2][s] + bins[3][s];
        atomicAdd(&imgbins[(size_t)img * 64 + tid], sum);
    }
}

// Pass 3: per-image weighted log-MSE contribution (one wave per image).
__global__ __launch_bounds__(256) void k_loss(const float* __restrict__ imgbins,
                                              const float* __restrict__ invcnt,
                                              const float* __restrict__ mean_cl,
                                              const float* __restrict__ weighting,
                                              float* __restrict__ out,
                                              float cscale, float invBN, int B) {
    const int tid = threadIdx.x, w = tid >> 6, lane = tid & 63;
    const int img = blockIdx.x * 4 + w;
    float acc = 0.0f;
    if (img < B) {
        const float v = imgbins[(size_t)img * 64 + lane] * cscale * invcnt[lane + 1];
        const float diff = logf(v + 1e-12f) - logf(mean_cl[lane] + 1e-12f);
        acc = weighting[lane] * diff * diff;
    }
    #pragma unroll
    for (int o = 32; o; o >>= 1) acc += __shfl_down(acc, o);
    if (lane == 0 && img < B) atomicAdd(out, acc * invBN);
}

__global__ void k_counts(const int* __restrict__ seg, float* __restrict__ invcnt, int n) {
    __shared__ int cnt[NB];
    const int tid = threadIdx.x;
    if (tid < NB) cnt[tid] = 0;
    __syncthreads();
    for (int i = tid; i < n; i += blockDim.x) atomicAdd(&cnt[seg[i]], 1);
    __syncthreads();
    if (tid < NB) invcnt[tid] = cnt[tid] > 0 ? 1.0f / (float)cnt[tid] : 0.0f;
}

extern "C" void kernel_launch(void* const* d_in, const int* in_sizes, int n_in,
                              void* d_out, int out_size, void* d_ws, size_t ws_size,
                              hipStream_t stream) {
    const float* pred      = (const float*)d_in[0];
    const float* mean_cl   = (const float*)d_in[1];
    const float* weighting = (const float*)d_in[2];
    const int*   seg       = (const int*)d_in[3];
    float* out = (float*)d_out;

    const int B = in_sizes[0] / 65536;

    // ws layout: [invcnt 1KB][imgbins B*64 f32][inter chunk area]
    float* invcnt  = (float*)d_ws;
    float* imgbins = (float*)((char*)d_ws + 1024);
    const size_t imgbins_bytes = ((size_t)B * 64 * sizeof(float) + 255) & ~(size_t)255;
    cplx* inter = (cplx*)((char*)d_ws + 1024 + imgbins_bytes);

    const size_t per_img = (size_t)129 * 256 * sizeof(cplx);   // 264192 B
    const size_t head = 1024 + imgbins_bytes;
    const size_t avail = ws_size > head ? ws_size - head : 0;
    int chunk = (int)(avail / per_img);
    if (chunk > B) chunk = B;
    if (chunk < 1) chunk = 1;

    const double rad = (5.0 * 60.0 / 256.0) * M_PI / 180.0;
    const float cscale = (float)(rad * rad / (65536.0 * 1e12)); // rad^2/N^2 / TSZ^2
    const float invBN  = (float)(1.0 / ((double)B * 64.0));

    hipMemsetAsync(d_out, 0, sizeof(float), stream);
    hipMemsetAsync(imgbins, 0, (size_t)B * 64 * sizeof(float), stream);
    k_counts<<<1, 256, 0, stream>>>(seg, invcnt, in_sizes[3]);

    for (int b0 = 0; b0 < B; b0 += chunk) {
        const int cb = (B - b0) < chunk ? (B - b0) : chunk;
        k_rowfft<<<cb * 32, 256, 0, stream>>>(pred + (size_t)b0 * 65536, inter);
        k_colfft<<<cb * 17, 256, 0, stream>>>(inter, seg, imgbins + (size_t)b0 * 64);
    }
    k_loss<<<(B + 3) / 4, 256, 0, stream>>>(imgbins, invcnt, mean_cl, weighting,
                                            out, cscale, invBN, B);
}

// Round 3
// 332.181 us; speedup vs baseline: 1.8732x; 1.5633x over previous
//
#include <hip/hip_runtime.h>
#include <hip/hip_fp16.h>
#include <math.h>

typedef float2 cplx;
#define PAD(f) ((f) + ((f) >> 4))   // +1 cplx every 16 (FFT work buffers)
#define NSEG 66                     // segments 0..65; valid bins 1..64

__device__ __forceinline__ cplx cmul(cplx a, cplx b) {
    return make_float2(a.x * b.x - a.y * b.y, a.x * b.y + a.y * b.x);
}

// Radix-4 DIT stages 0..2 on a wave-private padded LDS buffer (input stored
// digit-reversed). Wave-synchronous: single-wave LDS ops are in-order, and the
// compiler cannot hoist loads past the stores (same base pointer, must-alias).
__device__ __forceinline__ void fft_stages012(cplx* buf, int lane, const cplx* tw) {
    {   // stage 0: quarter=1, twiddles are all 1
        const int base = lane << 2;
        cplx t0 = buf[PAD(base)],     t1 = buf[PAD(base + 1)];
        cplx t2 = buf[PAD(base + 2)], t3 = buf[PAD(base + 3)];
        cplx a = {t0.x + t2.x, t0.y + t2.y}, b = {t0.x - t2.x, t0.y - t2.y};
        cplx c = {t1.x + t3.x, t1.y + t3.y}, d = {t1.x - t3.x, t1.y - t3.y};
        buf[PAD(base)]     = {a.x + c.x, a.y + c.y};
        buf[PAD(base + 1)] = {b.x + d.y, b.y - d.x};
        buf[PAD(base + 2)] = {a.x - c.x, a.y - c.y};
        buf[PAD(base + 3)] = {b.x - d.y, b.y + d.x};
    }
    #pragma unroll
    for (int s = 1; s < 3; ++s) {
        const int qsh = 2 * s;
        const int quarter = 1 << qsh;
        const int p = lane & (quarter - 1);
        const int g = lane >> qsh;
        const int base = (g << (qsh + 2)) + p;
        const int e = p << (6 - qsh);
        cplx t0 = buf[PAD(base)];
        cplx t1 = buf[PAD(base + quarter)];
        cplx t2 = buf[PAD(base + 2 * quarter)];
        cplx t3 = buf[PAD(base + 3 * quarter)];
        t1 = cmul(t1, tw[e]); t2 = cmul(t2, tw[2 * e]); t3 = cmul(t3, tw[3 * e]);
        cplx a = {t0.x + t2.x, t0.y + t2.y}, b = {t0.x - t2.x, t0.y - t2.y};
        cplx c = {t1.x + t3.x, t1.y + t3.y}, d = {t1.x - t3.x, t1.y - t3.y};
        buf[PAD(base)]               = {a.x + c.x, a.y + c.y};
        buf[PAD(base + quarter)]     = {b.x + d.y, b.y - d.x};
        buf[PAD(base + 2 * quarter)] = {a.x - c.x, a.y - c.y};
        buf[PAD(base + 3 * quarter)] = {b.x - d.y, b.y + d.x};
    }
}

// Stage 3 (quarter=64): outputs stay in registers; o[q] = F[lane + 64q].
__device__ __forceinline__ void fft_stage3(const cplx* buf, int lane, const cplx* tw, cplx o[4]) {
    cplx t0 = buf[PAD(lane)];
    cplx t1 = buf[PAD(lane + 64)];
    cplx t2 = buf[PAD(lane + 128)];
    cplx t3 = buf[PAD(lane + 192)];
    t1 = cmul(t1, tw[lane]); t2 = cmul(t2, tw[2 * lane]); t3 = cmul(t3, tw[3 * lane]);
    cplx a = {t0.x + t2.x, t0.y + t2.y}, b = {t0.x - t2.x, t0.y - t2.y};
    cplx c = {t1.x + t3.x, t1.y + t3.y}, d = {t1.x - t3.x, t1.y - t3.y};
    o[0] = {a.x + c.x, a.y + c.y};
    o[1] = {b.x + d.y, b.y - d.x};
    o[2] = {a.x - c.x, a.y - c.y};
    o[3] = {b.x - d.y, b.y + d.x};
}

// One workgroup per image: row FFTs -> half2 LDS tile [kx][y] (XOR-swizzled),
// column FFTs -> |F|^2 -> prefix-scan segmented binning -> per-image loss.
__global__ __launch_bounds__(512, 1)
void k_fused(const float* __restrict__ pred, const int4* __restrict__ tbl,
             const float* __restrict__ invcnt, const float* __restrict__ mean_cl,
             const float* __restrict__ weighting, float* __restrict__ out,
             float cscale, float invB64) {
    __shared__ __align__(16) __half2 tile[129 * 256];   // 132096 B
    __shared__ __align__(16) cplx rowbuf[8][272];       //  17408 B
    __shared__ cplx tw[256];                            //   2048 B
    const int tid = threadIdx.x, w = tid >> 6, lane = tid & 63;
    const int img = blockIdx.x;

    if (tid < 256) {
        float sg, cg;
        __sincosf(-6.283185307179586f * (float)tid / 256.0f, &sg, &cg);
        tw[tid] = make_float2(cg, sg);
    }
    __syncthreads();

    cplx* buf = rowbuf[w];
    // digit-reversal helpers
    const int bl = ((lane & 3) << 4) | (((lane >> 2) & 3) << 2) | (lane >> 4);       // row phase
    const int rl = ((lane & 3) << 6) | (((lane >> 2) & 3) << 4) | (((lane >> 4) & 3) << 2); // col phase

    // ---------------- row phase: 32 rows per wave ----------------
    const float* base = pred + (size_t)img * 65536;
    float4 cur = ((const float4*)(base + (size_t)(w * 32) * 256))[lane];
    for (int i = 0; i < 32; ++i) {
        const int y = w * 32 + i;
        float4 nxt = cur;
        if (i < 31) nxt = ((const float4*)(base + (size_t)(y + 1) * 256))[lane];
        // scatter digit-reversed: x[4l+r] -> buf[PAD(r*64 + bl)]
        buf[PAD(bl)]       = {cur.x, 0.0f};
        buf[PAD(bl + 64)]  = {cur.y, 0.0f};
        buf[PAD(bl + 128)] = {cur.z, 0.0f};
        buf[PAD(bl + 192)] = {cur.w, 0.0f};
        fft_stages012(buf, lane, tw);
        cplx o[4];
        fft_stage3(buf, lane, tw, o);        // o[q] = row-FFT at kx = lane + 64q
        const int ysw = y ^ (lane & 31);     // swizzle; (lane+64)&31 == lane&31
        tile[lane * 256 + ysw]        = __floats2half2_rn(o[0].x, o[0].y);
        tile[(lane + 64) * 256 + ysw] = __floats2half2_rn(o[1].x, o[1].y);
        if (lane == 0) tile[128 * 256 + y] = __floats2half2_rn(o[2].x, o[2].y); // kx=128, c=0
        cur = nxt;
    }
    __syncthreads();

    // ---------------- column phase: kx = w + 8t ----------------
    float acc = 0.0f;                        // this lane accumulates bin (lane+1)
    float* pbuf = (float*)buf;               // aliases rowbuf[w] (free after stage3)
    for (int t = 0; t < 17; ++t) {
        const int kx = w + 8 * t;
        if (kx > 128) break;
        const int c = kx & 31;
        // gather column (ky = lane + 64q), scatter digit-reversed into buf
        #pragma unroll
        for (int q = 0; q < 4; ++q) {
            const __half2 h = tile[kx * 256 + 64 * q + (lane ^ c)];
            const float2 v = __half22float2(h);
            buf[PAD(rl + q)] = {v.x, v.y};
        }
        fft_stages012(buf, lane, tw);
        cplx o[4];
        fft_stage3(buf, lane, tw, o);        // F[ky = lane + 64q]
        // powers to LDS in natural ky order (stride-64 scalar stores: conflict-free)
        pbuf[lane]       = o[0].x * o[0].x + o[0].y * o[0].y;
        pbuf[lane + 64]  = o[1].x * o[1].x + o[1].y * o[1].y;
        pbuf[lane + 128] = o[2].x * o[2].x + o[2].y * o[2].y;
        pbuf[lane + 192] = o[3].x * o[3].x + o[3].y * o[3].y;
        if (lane == 0) pbuf[256] = 0.0f;     // sentinel for empty/zero-start runs
        // inclusive prefix sum over 256 values
        const float4 pv = ((const float4*)pbuf)[lane];
        const float s0 = pv.x, s1 = s0 + pv.y, s2 = s1 + pv.z, s3 = s2 + pv.w;
        float x = s3;
        #pragma unroll
        for (int off = 1; off < 64; off <<= 1) {
            const float yv = __shfl_up(x, off);
            if (lane >= off) x += yv;
        }
        const float excl = x - s3;
        ((float4*)pbuf)[lane] = make_float4(excl + s0, excl + s1, excl + s2, excl + s3);
        // bin (lane+1): two contiguous ky-runs -> 4 prefix lookups
        const int4 tb = tbl[kx * 64 + lane];  // (lo1-1|256, hi1|256, lo2-1|256, hi2|256)
        const float csum = pbuf[tb.y] - pbuf[tb.x] + pbuf[tb.w] - pbuf[tb.z];
        const float symw = (kx == 0 || kx == 128) ? 1.0f : 2.0f;
        acc = fmaf(symw, csum, acc);
    }
    __syncthreads();

    // ---------------- reduce 8 waves, per-image loss ----------------
    float* bins8 = (float*)tile;             // tile is dead now
    bins8[w * 64 + lane] = acc;
    __syncthreads();
    if (tid < 64) {
        float tot = 0.0f;
        #pragma unroll
        for (int ww = 0; ww < 8; ++ww) tot += bins8[ww * 64 + tid];
        const float v = tot * cscale * invcnt[tid + 1];
        const float diff = logf(v + 1e-12f) - logf(mean_cl[tid] + 1e-12f);
        float l = weighting[tid] * diff * diff;
        #pragma unroll
        for (int off = 32; off; off >>= 1) l += __shfl_down(l, off);
        if (tid == 0) atomicAdd(out, l * invB64);
    }
}

// Boundary table: for each kx (0..128) and bin b (seg=b+1), the <=2 contiguous
// ky-runs (monotone radius for ky 0..128, mirrored for 129..255), encoded as
// prefix-lookup indices with 256 as the "zero" sentinel slot.
__global__ void k_bounds(const int* __restrict__ seg, int4* __restrict__ tbl) {
    __shared__ int lo1[NSEG], hi1[NSEG], lo2[NSEG], hi2[NSEG];
    const int kx = blockIdx.x, ky = threadIdx.x;
    if (ky < NSEG) { lo1[ky] = 300; hi1[ky] = -1; lo2[ky] = 300; hi2[ky] = -1; }
    __syncthreads();
    const int s = seg[kx * 256 + ky];        // seg is symmetric in (kx,ky)
    if (ky <= 128) { atomicMin(&lo1[s], ky); atomicMax(&hi1[s], ky); }
    else           { atomicMin(&lo2[s], ky); atomicMax(&hi2[s], ky); }
    __syncthreads();
    if (ky >= 1 && ky <= 64) {
        int4 t;
        if (hi1[ky] < 0) { t.x = 256; t.y = 256; }
        else             { t.x = (lo1[ky] > 0) ? lo1[ky] - 1 : 256; t.y = hi1[ky]; }
        if (hi2[ky] < 0) { t.z = 256; t.w = 256; }
        else             { t.z = lo2[ky] - 1; t.w = hi2[ky]; }
        tbl[kx * 64 + (ky - 1)] = t;
    }
}

__global__ void k_counts(const int* __restrict__ seg, float* __restrict__ invcnt, int n) {
    __shared__ int cnt[NSEG];
    const int tid = threadIdx.x;
    if (tid < NSEG) cnt[tid] = 0;
    __syncthreads();
    for (int i = tid; i < n; i += blockDim.x) atomicAdd(&cnt[seg[i]], 1);
    __syncthreads();
    if (tid < NSEG) invcnt[tid] = cnt[tid] > 0 ? 1.0f / (float)cnt[tid] : 0.0f;
}

extern "C" void kernel_launch(void* const* d_in, const int* in_sizes, int n_in,
                              void* d_out, int out_size, void* d_ws, size_t ws_size,
                              hipStream_t stream) {
    const float* pred      = (const float*)d_in[0];
    const float* mean_cl   = (const float*)d_in[1];
    const float* weighting = (const float*)d_in[2];
    const int*   seg       = (const int*)d_in[3];
    float* out = (float*)d_out;

    const int B = in_sizes[0] / 65536;

    // ws: [invcnt 66 f32, pad to 256B][boundary table 129*64 int4 = 132096B]
    float* invcnt = (float*)d_ws;
    int4*  tbl    = (int4*)((char*)d_ws + 256);

    const double rad = (5.0 * 60.0 / 256.0) * M_PI / 180.0;
    const float cscale = (float)(rad * rad / (65536.0 * 1e12)); // rad^2/N^2 / TSZ^2
    const float invB64 = (float)(1.0 / ((double)B * 64.0));

    hipMemsetAsync(d_out, 0, sizeof(float), stream);
    k_counts<<<1, 256, 0, stream>>>(seg, invcnt, in_sizes[3]);
    k_bounds<<<129, 256, 0, stream>>>(seg, tbl);
    k_fused<<<B, 512, 0, stream>>>(pred, tbl, invcnt, mean_cl, weighting,
                                   out, cscale, invB64);
}

// Round 4
// 281.369 us; speedup vs baseline: 2.2115x; 1.1806x over previous
//
#include <hip/hip_runtime.h>
#include <hip/hip_fp16.h>
#include <math.h>

#define NSEG 66                 // segments 0..65; valid bins 1..64
typedef float2 cplx;

__device__ __forceinline__ cplx cmul(cplx a, cplx b) {
    return make_float2(a.x*b.x - a.y*b.y, a.x*b.y + a.y*b.x);
}
__device__ __forceinline__ int brev6(int l) {
    return ((l&1)<<5)|((l&2)<<3)|((l&4)<<1)|((l&8)>>1)|((l&16)>>3)|((l&32)>>5);
}
__device__ __forceinline__ float2 h2f(unsigned u) {
    __half2 h; *reinterpret_cast<unsigned*>(&h) = u; return __half22float2(h);
}
__device__ __forceinline__ unsigned f2h(float a, float b) {
    __half2 h = __floats2half2_rn(a, b); return *reinterpret_cast<unsigned*>(&h);
}

// Per-lane constants for the four-step 256-pt FFT (all in registers).
struct XT {
    float2 t32, t16, t8, t4, t2;   // stage twiddles of the 64-pt xor network
    float  s32, s16, s8, s4, s2, s1; // butterfly sign per stage
    float2 w1, w2, w3;             // W256^{brev(L)}, ^2, ^3
    int    pl;                     // Hermitian partner lane
};

// One radix-2 DIF butterfly at xor-distance d.
// lanes (L&d)==0: u = z + partner, *1 ; lanes (L&d)!=0: u = partner - z, *tw
__device__ __forceinline__ float2 bfly(float2 z, int d, float sg, float2 tw) {
    float2 c; c.x = __shfl_xor(z.x, d); c.y = __shfl_xor(z.y, d);
    float ux = fmaf(sg, z.x, c.x), uy = fmaf(sg, z.y, c.y);
    return make_float2(ux*tw.x - uy*tw.y, ux*tw.y + uy*tw.x);
}
__device__ __forceinline__ float2 bfly1(float2 z, float sg) {  // d=1, tw==1
    float2 c; c.x = __shfl_xor(z.x, 1); c.y = __shfl_xor(z.y, 1);
    return make_float2(fmaf(sg, z.x, c.x), fmaf(sg, z.y, c.y));
}
// Four independent 64-pt FFTs (one per register), natural lane order in,
// bit-reversed lane order out: result at lane L is G[brev6(L)].
__device__ __forceinline__ void fft64x4(float2 z[4], const XT& T) {
    #pragma unroll
    for (int a = 0; a < 4; ++a) {
        z[a] = bfly(z[a], 32, T.s32, T.t32);
        z[a] = bfly(z[a], 16, T.s16, T.t16);
        z[a] = bfly(z[a],  8, T.s8,  T.t8);
        z[a] = bfly(z[a],  4, T.s4,  T.t4);
        z[a] = bfly(z[a],  2, T.s2,  T.t2);
        z[a] = bfly1(z[a], T.s1);
    }
}
// Twiddle by W256^{a*brev(L)} then in-lane DFT4: X[q] = F[brev6(L) + 64q].
__device__ __forceinline__ void twdft4(const float2 z[4], const XT& T, float2 X[4]) {
    float2 g0 = z[0], g1 = cmul(z[1], T.w1), g2 = cmul(z[2], T.w2), g3 = cmul(z[3], T.w3);
    float2 b0 = {g0.x+g2.x, g0.y+g2.y}, b1 = {g0.x-g2.x, g0.y-g2.y};
    float2 b2 = {g1.x+g3.x, g1.y+g3.y}, b3 = {g1.x-g3.x, g1.y-g3.y};
    X[0] = {b0.x+b2.x, b0.y+b2.y};
    X[2] = {b0.x-b2.x, b0.y-b2.y};
    X[1] = {b1.x+b3.y, b1.y-b3.x};   // b1 - i*b3
    X[3] = {b1.x-b3.y, b1.y+b3.x};   // b1 + i*b3
}

// One 1024-thread workgroup per image. Row-pair FFTs (real-pack) -> half2 LDS
// tile [kx][y^(kx&28)] -> column FFTs -> |F|^2 -> prefix-scan binning -> loss.
__global__ __launch_bounds__(1024)
void k_fused(const float* __restrict__ pred, const int4* __restrict__ tbl,
             const float* __restrict__ invcnt, const float* __restrict__ mean_cl,
             const float* __restrict__ weighting, float* __restrict__ out,
             float cscale, float invB64) {
    __shared__ __align__(16) unsigned tile[129 * 256];   // half2 as u32, 132096 B
    __shared__ __align__(16) float pbuf[16][260];        // per-wave scan buffer
    const int tid = threadIdx.x, w = tid >> 6, L = tid & 63;
    const int rL = brev6(L);
    const float PI2 = 6.283185307179586f;

    XT T;
    {
        float sg, cg;
        auto stw = [&](int d, float2& t, float& s) {
            s = (L & d) ? -1.f : 1.f;
            const int e = (L & d) ? (L & (d-1)) * (32/d) : 0;
            float ss, cc; __sincosf(-PI2 * (float)e / 64.f, &ss, &cc);
            t = make_float2(cc, ss);
        };
        stw(32, T.t32, T.s32); stw(16, T.t16, T.s16); stw(8, T.t8, T.s8);
        stw(4, T.t4, T.s4); stw(2, T.t2, T.s2);
        T.s1 = (L & 1) ? -1.f : 1.f;
        __sincosf(-PI2 * (float)rL / 256.f, &sg, &cg);
        T.w1 = make_float2(cg, sg);
        T.w2 = cmul(T.w1, T.w1);
        T.w3 = cmul(T.w2, T.w1);
        T.pl = brev6((64 - rL) & 63);
    }

    // ---------------- row phase: 8 row-pairs per wave ----------------
    const float* base = pred + (size_t)blockIdx.x * 65536;
    const int sw = rL & 28;
    #pragma unroll 1
    for (int t = 0; t < 8; ++t) {
        const int y = 16*w + 2*t;
        const float4 ra = *(const float4*)(base + (size_t)y*256 + 4*L);
        const float4 rb = *(const float4*)(base + (size_t)(y+1)*256 + 4*L);
        float2 z[4] = {{ra.x,rb.x},{ra.y,rb.y},{ra.z,rb.z},{ra.w,rb.w}};
        fft64x4(z, T);                  // z = packed-FFT Z at kx=brev(L)+64q
        float2 X[4]; twdft4(z, T, X);
        // Hermitian unpack partners: conj(Z[256-kx])
        float2 q0, q1;
        q0.x = __shfl(X[3].x, T.pl); q0.y = __shfl(X[3].y, T.pl);
        q1.x = __shfl(X[2].x, T.pl); q1.y = __shfl(X[2].y, T.pl);
        if (L == 0) { q0 = X[0]; q1 = X[3]; }   // kx=0 and kx=64 self/reg fixes
        const int yi = y ^ sw;                   // y even, sw low2=0 -> +1 ok
        {   // kx = rL:  F_y = 0.5(A+conj(q)),  F_{y+1} = -0.5i(A-conj(q))
            const float fx = 0.5f*(X[0].x + q0.x), fy = 0.5f*(X[0].y - q0.y);
            const float gx = 0.5f*(X[0].y + q0.y), gy = -0.5f*(X[0].x - q0.x);
            uint2 pk; pk.x = f2h(fx, fy); pk.y = f2h(gx, gy);
            *(uint2*)&tile[rL*256 + yi] = pk;
        }
        {   // kx = 64 + rL  (same swizzle: (64+rL)&28 == rL&28)
            const float fx = 0.5f*(X[1].x + q1.x), fy = 0.5f*(X[1].y - q1.y);
            const float gx = 0.5f*(X[1].y + q1.y), gy = -0.5f*(X[1].x - q1.x);
            uint2 pk; pk.x = f2h(fx, fy); pk.y = f2h(gx, gy);
            *(uint2*)&tile[(64+rL)*256 + yi] = pk;
        }
        if (L == 0) {   // kx = 128: Z[128] self-conjugate -> F=(Re, Im)
            uint2 pk; pk.x = f2h(X[2].x, 0.f); pk.y = f2h(X[2].y, 0.f);
            *(uint2*)&tile[128*256 + y] = pk;
        }
    }
    __syncthreads();

    // ---------------- column phase: kx = w + 16t ----------------
    float acc = 0.f;                   // lane accumulates bin (L+1)
    float* pb = pbuf[w];
    #pragma unroll 1
    for (int kx = w; kx <= 128; kx += 16) {
        const int cs = kx & 28;
        const uint4 uu = *(const uint4*)&tile[kx*256 + ((4*L) ^ cs)];
        float2 z[4] = { h2f(uu.x), h2f(uu.y), h2f(uu.z), h2f(uu.w) }; // x[4L+a]
        fft64x4(z, T);
        float2 X[4]; twdft4(z, T, X);  // X[q] = F[ky = brev(L) + 64q]
        pb[rL]       = X[0].x*X[0].x + X[0].y*X[0].y;   // natural-order scatter
        pb[rL + 64]  = X[1].x*X[1].x + X[1].y*X[1].y;
        pb[rL + 128] = X[2].x*X[2].x + X[2].y*X[2].y;
        pb[rL + 192] = X[3].x*X[3].x + X[3].y*X[3].y;
        if (L == 0) pb[256] = 0.f;     // sentinel for empty/zero-start runs
        const float4 pv = ((const float4*)pb)[L];
        const float s0 = pv.x, s1 = s0+pv.y, s2 = s1+pv.z, s3 = s2+pv.w;
        float x = s3;
        #pragma unroll
        for (int off = 1; off < 64; off <<= 1) {
            const float yv = __shfl_up(x, off);
            if (L >= off) x += yv;
        }
        const float ex = x - s3;       // exclusive prefix of the lane's 4-group
        ((float4*)pb)[L] = make_float4(ex+s0, ex+s1, ex+s2, ex+s3);
        const int4 tb = tbl[kx*64 + L];  // <=2 ky-runs as prefix indices
        const float csum = pb[tb.y] - pb[tb.x] + pb[tb.w] - pb[tb.z];
        const float symw = (kx == 0 || kx == 128) ? 1.f : 2.f;
        acc = fmaf(symw, csum, acc);
    }
    __syncthreads();

    // ---------------- reduce 16 waves, per-image loss ----------------
    float* bins = (float*)tile;        // tile dead now
    bins[w*64 + L] = acc;
    __syncthreads();
    if (tid < 64) {
        float tot = 0.f;
        #pragma unroll
        for (int ww = 0; ww < 16; ++ww) tot += bins[ww*64 + tid];
        const float v = tot * cscale * invcnt[tid + 1];
        const float d = logf(v + 1e-12f) - logf(mean_cl[tid] + 1e-12f);
        float l = weighting[tid] * d * d;
        #pragma unroll
        for (int o = 32; o; o >>= 1) l += __shfl_down(l, o);
        if (tid == 0) atomicAdd(out, l * invB64);
    }
}

// Boundary table: per (kx, bin) the <=2 contiguous ky-runs (radius monotone
// for ky 0..128, mirrored above), as prefix-lookup indices; 256 = zero slot.
__global__ void k_bounds(const int* __restrict__ seg, int4* __restrict__ tbl) {
    __shared__ int lo1[NSEG], hi1[NSEG], lo2[NSEG], hi2[NSEG];
    const int kx = blockIdx.x, ky = threadIdx.x;
    if (ky < NSEG) { lo1[ky] = 300; hi1[ky] = -1; lo2[ky] = 300; hi2[ky] = -1; }
    __syncthreads();
    const int s = seg[kx * 256 + ky];     // seg symmetric in (kx,ky)
    if (ky <= 128) { atomicMin(&lo1[s], ky); atomicMax(&hi1[s], ky); }
    else           { atomicMin(&lo2[s], ky); atomicMax(&hi2[s], ky); }
    __syncthreads();
    if (ky >= 1 && ky <= 64) {
        int4 t;
        if (hi1[ky] < 0) { t.x = 256; t.y = 256; }
        else             { t.x = (lo1[ky] > 0) ? lo1[ky] - 1 : 256; t.y = hi1[ky]; }
        if (hi2[ky] < 0) { t.z = 256; t.w = 256; }
        else             { t.z = lo2[ky] - 1; t.w = hi2[ky]; }
        tbl[kx * 64 + (ky - 1)] = t;
    }
}

__global__ void k_counts(const int* __restrict__ seg, float* __restrict__ invcnt, int n) {
    __shared__ int cnt[NSEG];
    const int tid = threadIdx.x;
    if (tid < NSEG) cnt[tid] = 0;
    __syncthreads();
    for (int i = tid; i < n; i += blockDim.x) atomicAdd(&cnt[seg[i]], 1);
    __syncthreads();
    if (tid < NSEG) invcnt[tid] = cnt[tid] > 0 ? 1.0f / (float)cnt[tid] : 0.0f;
}

extern "C" void kernel_launch(void* const* d_in, const int* in_sizes, int n_in,
                              void* d_out, int out_size, void* d_ws, size_t ws_size,
                              hipStream_t stream) {
    const float* pred      = (const float*)d_in[0];
    const float* mean_cl   = (const float*)d_in[1];
    const float* weighting = (const float*)d_in[2];
    const int*   seg       = (const int*)d_in[3];
    float* out = (float*)d_out;

    const int B = in_sizes[0] / 65536;

    // ws: [invcnt 66 f32, pad to 256B][boundary table 129*64 int4]
    float* invcnt = (float*)d_ws;
    int4*  tbl    = (int4*)((char*)d_ws + 256);

    const double rad = (5.0 * 60.0 / 256.0) * M_PI / 180.0;
    const float cscale = (float)(rad * rad / (65536.0 * 1e12)); // rad^2/N^2/TSZ^2
    const float invB64 = (float)(1.0 / ((double)B * 64.0));

    hipMemsetAsync(d_out, 0, sizeof(float), stream);
    k_counts<<<1, 256, 0, stream>>>(seg, invcnt, in_sizes[3]);
    k_bounds<<<129, 256, 0, stream>>>(seg, tbl);
    k_fused<<<B, 1024, 0, stream>>>(pred, tbl, invcnt, mean_cl, weighting,
                                    out, cscale, invB64);
}

// Round 6
// 198.698 us; speedup vs baseline: 3.1316x; 1.4161x over previous
//
#include <hip/hip_runtime.h>
#include <hip/hip_fp16.h>
#include <math.h>

#define NSEG 66                 // segments 0..65; valid bins 1..64
typedef float2 cplx;

__device__ __forceinline__ cplx cmul(cplx a, cplx b) {
    return make_float2(a.x*b.x - a.y*b.y, a.x*b.y + a.y*b.x);
}
__device__ __forceinline__ int brev6(int l) {
    return ((l&1)<<5)|((l&2)<<3)|((l&4)<<1)|((l&8)>>1)|((l&16)>>3)|((l&32)>>5);
}
__device__ __forceinline__ float2 h2f(unsigned u) {
    __half2 h; *reinterpret_cast<unsigned*>(&h) = u; return __half22float2(h);
}
__device__ __forceinline__ unsigned f2h(float a, float b) {
    __half2 h = __floats2half2_rn(a, b); return *reinterpret_cast<unsigned*>(&h);
}

// Per-lane constants for the four-step 256-pt FFT (all in registers).
struct XT {
    float2 t32, t16, t8, t4, t2;     // stage twiddles of the 64-pt xor network
    float  s32, s16, s8, s4, s2, s1; // butterfly sign per stage
    float2 w1, w2, w3;               // W256^{brev(L)}, ^2, ^3
    int    pl;                       // Hermitian partner lane
};

// One radix-2 DIF butterfly at xor-distance d.
__device__ __forceinline__ float2 bfly(float2 z, int d, float sg, float2 tw) {
    float2 c; c.x = __shfl_xor(z.x, d); c.y = __shfl_xor(z.y, d);
    float ux = fmaf(sg, z.x, c.x), uy = fmaf(sg, z.y, c.y);
    return make_float2(ux*tw.x - uy*tw.y, ux*tw.y + uy*tw.x);
}
__device__ __forceinline__ float2 bfly1(float2 z, float sg) {  // d=1, tw==1
    float2 c; c.x = __shfl_xor(z.x, 1); c.y = __shfl_xor(z.y, 1);
    return make_float2(fmaf(sg, z.x, c.x), fmaf(sg, z.y, c.y));
}
// Four independent 64-pt FFTs; natural lane order in, result at lane L is G[brev6(L)].
__device__ __forceinline__ void fft64x4(float2 z[4], const XT& T) {
    #pragma unroll
    for (int a = 0; a < 4; ++a) {
        z[a] = bfly(z[a], 32, T.s32, T.t32);
        z[a] = bfly(z[a], 16, T.s16, T.t16);
        z[a] = bfly(z[a],  8, T.s8,  T.t8);
        z[a] = bfly(z[a],  4, T.s4,  T.t4);
        z[a] = bfly(z[a],  2, T.s2,  T.t2);
        z[a] = bfly1(z[a], T.s1);
    }
}
// Twiddle by W256^{a*brev(L)} then in-lane DFT4: X[q] = F[brev6(L) + 64q].
__device__ __forceinline__ void twdft4(const float2 z[4], const XT& T, float2 X[4]) {
    float2 g0 = z[0], g1 = cmul(z[1], T.w1), g2 = cmul(z[2], T.w2), g3 = cmul(z[3], T.w3);
    float2 b0 = {g0.x+g2.x, g0.y+g2.y}, b1 = {g0.x-g2.x, g0.y-g2.y};
    float2 b2 = {g1.x+g3.x, g1.y+g3.y}, b3 = {g1.x-g3.x, g1.y-g3.y};
    X[0] = {b0.x+b2.x, b0.y+b2.y};
    X[2] = {b0.x-b2.x, b0.y-b2.y};
    X[1] = {b1.x+b3.y, b1.y-b3.x};   // b1 - i*b3
    X[3] = {b1.x-b3.y, b1.y+b3.x};   // b1 + i*b3
}

// One 1024-thread workgroup per image. Row-pair FFTs (real-pack) -> half2 LDS
// tile [kx][y^(kx&28)] -> column FFTs -> |F|^2 -> prefix-scan binning -> loss.
__global__ __launch_bounds__(1024)
void k_fused(const float* __restrict__ pred, const int4* __restrict__ tbl,
             const int* __restrict__ cnt, const float* __restrict__ mean_cl,
             const float* __restrict__ weighting, float* __restrict__ out,
             float cscale, float invB64) {
    __shared__ __align__(16) unsigned tile[129 * 256];   // half2 as u32, 132096 B
    __shared__ __align__(16) float pbuf[16][260];        // per-wave scan buffer
    const int tid = threadIdx.x, w = tid >> 6, L = tid & 63;
    const int rL = brev6(L);
    const float PI2 = 6.283185307179586f;

    XT T;
    {
        float sg, cg;
        auto stw = [&](int d, float2& t, float& s) {
            s = (L & d) ? -1.f : 1.f;
            const int e = (L & d) ? (L & (d-1)) * (32/d) : 0;
            float ss, cc; __sincosf(-PI2 * (float)e / 64.f, &ss, &cc);
            t = make_float2(cc, ss);
        };
        stw(32, T.t32, T.s32); stw(16, T.t16, T.s16); stw(8, T.t8, T.s8);
        stw(4, T.t4, T.s4); stw(2, T.t2, T.s2);
        T.s1 = (L & 1) ? -1.f : 1.f;
        __sincosf(-PI2 * (float)rL / 256.f, &sg, &cg);
        T.w1 = make_float2(cg, sg);
        T.w2 = cmul(T.w1, T.w1);
        T.w3 = cmul(T.w2, T.w1);
        T.pl = brev6((64 - rL) & 63);
    }

    // ---------------- row phase: 8 row-pairs per wave ----------------
    const float* base = pred + (size_t)blockIdx.x * 65536;
    const int sw = rL & 28;
    #pragma unroll 2
    for (int t = 0; t < 8; ++t) {
        const int y = 16*w + 2*t;
        const float4 ra = *(const float4*)(base + (size_t)y*256 + 4*L);
        const float4 rb = *(const float4*)(base + (size_t)(y+1)*256 + 4*L);
        float2 z[4] = {{ra.x,rb.x},{ra.y,rb.y},{ra.z,rb.z},{ra.w,rb.w}};
        fft64x4(z, T);                  // z = packed-FFT Z at kx=brev(L)+64q
        float2 X[4]; twdft4(z, T, X);
        // Hermitian unpack partners: conj(Z[256-kx])
        float2 q0, q1;
        q0.x = __shfl(X[3].x, T.pl); q0.y = __shfl(X[3].y, T.pl);
        q1.x = __shfl(X[2].x, T.pl); q1.y = __shfl(X[2].y, T.pl);
        if (L == 0) { q0 = X[0]; q1 = X[3]; }   // kx=0 and kx=64 fixes
        const int yi = y ^ sw;                   // y even, sw low2=0 -> +1 ok
        {   // kx = rL:  F_y = 0.5(A+conj(q)),  F_{y+1} = -0.5i(A-conj(q))
            const float fx = 0.5f*(X[0].x + q0.x), fy = 0.5f*(X[0].y - q0.y);
            const float gx = 0.5f*(X[0].y + q0.y), gy = -0.5f*(X[0].x - q0.x);
            uint2 pk; pk.x = f2h(fx, fy); pk.y = f2h(gx, gy);
            *(uint2*)&tile[rL*256 + yi] = pk;
        }
        {   // kx = 64 + rL  (same swizzle: (64+rL)&28 == rL&28)
            const float fx = 0.5f*(X[1].x + q1.x), fy = 0.5f*(X[1].y - q1.y);
            const float gx = 0.5f*(X[1].y + q1.y), gy = -0.5f*(X[1].x - q1.x);
            uint2 pk; pk.x = f2h(fx, fy); pk.y = f2h(gx, gy);
            *(uint2*)&tile[(64+rL)*256 + yi] = pk;
        }
        if (L == 0) {   // kx = 128: Z[128] self-conjugate -> F=(Re, Im)
            uint2 pk; pk.x = f2h(X[2].x, 0.f); pk.y = f2h(X[2].y, 0.f);
            *(uint2*)&tile[128*256 + y] = pk;
        }
    }
    __syncthreads();

    // ---------------- column phase: kx = w + 16t ----------------
    float acc = 0.f;                   // lane accumulates bin (L+1)
    float* pb = pbuf[w];
    if (L == 0) pb[256] = 0.f;         // sentinel (float4 stores cover 0..255 only)
    #pragma unroll 1
    for (int kx = w; kx <= 128; kx += 16) {
        const int cs = kx & 28;
        const int4 tb = tbl[kx*64 + L];  // <=2 ky-runs as prefix indices (early issue)
        const uint4 uu = *(const uint4*)&tile[kx*256 + ((4*L) ^ cs)];
        float2 z[4] = { h2f(uu.x), h2f(uu.y), h2f(uu.z), h2f(uu.w) }; // x[4L+a]
        fft64x4(z, T);
        float2 X[4]; twdft4(z, T, X);  // X[q] = F[ky = brev(L) + 64q]
        pb[rL]       = X[0].x*X[0].x + X[0].y*X[0].y;   // natural-order scatter
        pb[rL + 64]  = X[1].x*X[1].x + X[1].y*X[1].y;
        pb[rL + 128] = X[2].x*X[2].x + X[2].y*X[2].y;
        pb[rL + 192] = X[3].x*X[3].x + X[3].y*X[3].y;
        const float4 pv = ((const float4*)pb)[L];
        const float s0 = pv.x, s1 = s0+pv.y, s2 = s1+pv.z, s3 = s2+pv.w;
        float x = s3;
        #pragma unroll
        for (int off = 1; off < 64; off <<= 1) {
            const float yv = __shfl_up(x, off);
            if (L >= off) x += yv;
        }
        const float ex = x - s3;       // exclusive prefix of the lane's 4-group
        ((float4*)pb)[L] = make_float4(ex+s0, ex+s1, ex+s2, ex+s3);
        const float csum = pb[tb.y] - pb[tb.x] + pb[tb.w] - pb[tb.z];
        const float symw = (kx == 0 || kx == 128) ? 1.f : 2.f;
        acc = fmaf(symw, csum, acc);
    }
    __syncthreads();

    // ---------------- reduce 16 waves, per-image loss ----------------
    float* bins = (float*)tile;        // tile dead now
    bins[w*64 + L] = acc;
    __syncthreads();
    if (tid < 64) {
        float tot = 0.f;
        #pragma unroll
        for (int ww = 0; ww < 16; ++ww) tot += bins[ww*64 + tid];
        const int c = cnt[tid + 1];
        const float inv = (c > 0) ? 1.0f / (float)c : 0.0f;
        const float v = tot * cscale * inv;
        const float d = logf(v + 1e-12f) - logf(mean_cl[tid] + 1e-12f);
        float l = weighting[tid] * d * d;
        #pragma unroll
        for (int o = 32; o; o >>= 1) l += __shfl_down(l, o);
        if (tid == 0) atomicAdd(out, l * invB64);
    }
}

// Prep: one block per kx row (0..255). All rows: per-segment counts (LDS hist
// -> global atomics). Rows 0..128 additionally emit the boundary table: per
// (kx, bin) the <=2 contiguous ky-runs (radius monotone for ky 0..128,
// mirrored above), as prefix-lookup indices; 256 = zero sentinel slot.
__global__ __launch_bounds__(256) void k_prep(const int* __restrict__ seg,
                                              int4* __restrict__ tbl,
                                              int* __restrict__ cnt) {
    __shared__ int lo1[NSEG], hi1[NSEG], lo2[NSEG], hi2[NSEG], lc[NSEG];
    const int kx = blockIdx.x, ky = threadIdx.x;
    if (ky < NSEG) { lo1[ky] = 300; hi1[ky] = -1; lo2[ky] = 300; hi2[ky] = -1; lc[ky] = 0; }
    __syncthreads();
    const int s = seg[kx * 256 + ky];
    atomicAdd(&lc[s], 1);
    if (kx <= 128) {
        if (ky <= 128) { atomicMin(&lo1[s], ky); atomicMax(&hi1[s], ky); }
        else           { atomicMin(&lo2[s], ky); atomicMax(&hi2[s], ky); }
    }
    __syncthreads();
    if (ky < NSEG && lc[ky] > 0) atomicAdd(&cnt[ky], lc[ky]);
    if (kx <= 128 && ky >= 1 && ky <= 64) {
        int4 t;
        if (hi1[ky] < 0) { t.x = 256; t.y = 256; }
        else             { t.x = (lo1[ky] > 0) ? lo1[ky] - 1 : 256; t.y = hi1[ky]; }
        if (hi2[ky] < 0) { t.z = 256; t.w = 256; }
        else             { t.z = lo2[ky] - 1; t.w = hi2[ky]; }
        tbl[kx * 64 + (ky - 1)] = t;
    }
}

extern "C" void kernel_launch(void* const* d_in, const int* in_sizes, int n_in,
                              void* d_out, int out_size, void* d_ws, size_t ws_size,
                              hipStream_t stream) {
    const float* pred      = (const float*)d_in[0];
    const float* mean_cl   = (const float*)d_in[1];
    const float* weighting = (const float*)d_in[2];
    const int*   seg       = (const int*)d_in[3];
    float* out = (float*)d_out;

    const int B = in_sizes[0] / 65536;

    // ws: [cnt 66 i32, pad to 256B][boundary table 129*64 int4]
    int*  cnt = (int*)d_ws;
    int4* tbl = (int4*)((char*)d_ws + 256);

    const double rad = (5.0 * 60.0 / 256.0) * M_PI / 180.0;
    const float cscale = (float)(rad * rad / (65536.0 * 1e12)); // rad^2/N^2/TSZ^2
    const float invB64 = (float)(1.0 / ((double)B * 64.0));

    hipMemsetAsync(d_out, 0, sizeof(float), stream);
    hipMemsetAsync(cnt, 0, NSEG * sizeof(int), stream);
    k_prep<<<256, 256, 0, stream>>>(seg, tbl, cnt);
    k_fused<<<B, 1024, 0, stream>>>(pred, tbl, cnt, mean_cl, weighting,
                                    out, cscale, invB64);
}

// Round 9
// 161.813 us; speedup vs baseline: 3.8455x; 1.2279x over previous
//
#include <hip/hip_runtime.h>
#include <hip/hip_fp16.h>
#include <math.h>

#define NSEG 66                 // segments 0..65; valid bins 1..64
typedef float2 cplx;
typedef unsigned uv2 __attribute__((ext_vector_type(2)));

__device__ __forceinline__ cplx cmul(cplx a, cplx b) {
    return make_float2(a.x*b.x - a.y*b.y, a.x*b.y + a.y*b.x);
}
__device__ __forceinline__ int brev6(int l) {
    return ((l&1)<<5)|((l&2)<<3)|((l&4)<<1)|((l&8)>>1)|((l&16)>>3)|((l&32)>>5);
}
__device__ __forceinline__ float2 h2f(unsigned u) {
    __half2 h; *reinterpret_cast<unsigned*>(&h) = u; return __half22float2(h);
}
__device__ __forceinline__ unsigned f2h(float a, float b) {
    __half2 h = __floats2half2_rn(a, b); return *reinterpret_cast<unsigned*>(&h);
}

// Per-lane constants for the four-step 256-pt FFT (all in registers).
struct XT {
    float2 t32, t16, t8, t4, t2;     // stage twiddles of the 64-pt xor network
    float  s32, s16, s8, s4, s2, s1; // butterfly sign per stage
    float2 w1, w2, w3;               // W256^{brev(L)}, ^2, ^3
    int    pl;                       // Hermitian partner lane
};

// ---- cross-lane exchange primitives (VALU where possible, DS only for d=4) ----
// d=32: v_permlane32_swap(z,z) -> ret0=[z_lo,z_lo], ret1=[z_hi,z_hi]
__device__ __forceinline__ float2 bfly_pl32(float2 z, float sg, float2 tw) {
#if __has_builtin(__builtin_amdgcn_permlane32_swap)
    uv2 rx = __builtin_amdgcn_permlane32_swap(__float_as_uint(z.x), __float_as_uint(z.x), false, false);
    uv2 ry = __builtin_amdgcn_permlane32_swap(__float_as_uint(z.y), __float_as_uint(z.y), false, false);
    float ux = fmaf(sg, __uint_as_float(rx[1]), __uint_as_float(rx[0]));
    float uy = fmaf(sg, __uint_as_float(ry[1]), __uint_as_float(ry[0]));
#else
    float cx = __shfl_xor(z.x, 32), cy = __shfl_xor(z.y, 32);
    float ux = fmaf(sg, z.x, cx), uy = fmaf(sg, z.y, cy);
#endif
    return make_float2(ux*tw.x - uy*tw.y, ux*tw.y + uy*tw.x);
}
// d=16: v_permlane16_swap(z,z) -> ret0=[r0,r0,r2,r2], ret1=[r1,r1,r3,r3]
__device__ __forceinline__ float2 bfly_pl16(float2 z, float sg, float2 tw) {
#if __has_builtin(__builtin_amdgcn_permlane16_swap)
    uv2 rx = __builtin_amdgcn_permlane16_swap(__float_as_uint(z.x), __float_as_uint(z.x), false, false);
    uv2 ry = __builtin_amdgcn_permlane16_swap(__float_as_uint(z.y), __float_as_uint(z.y), false, false);
    float ux = fmaf(sg, __uint_as_float(rx[1]), __uint_as_float(rx[0]));
    float uy = fmaf(sg, __uint_as_float(ry[1]), __uint_as_float(ry[0]));
#else
    float cx = __shfl_xor(z.x, 16), cy = __shfl_xor(z.y, 16);
    float ux = fmaf(sg, z.x, cx), uy = fmaf(sg, z.y, cy);
#endif
    return make_float2(ux*tw.x - uy*tw.y, ux*tw.y + uy*tw.x);
}
// DPP xor-permutes: row_ror:8 (0x128) = xor8; quad_perm 0x4E = xor2; 0xB1 = xor1
template<int CTRL>
__device__ __forceinline__ float dppx(float x) {
#if __has_builtin(__builtin_amdgcn_update_dpp)
    return __int_as_float(__builtin_amdgcn_update_dpp(
        __float_as_int(x), __float_as_int(x), CTRL, 0xF, 0xF, false));
#else
    const int d = (CTRL == 0x128) ? 8 : (CTRL == 0x4E ? 2 : 1);
    return __shfl_xor(x, d);
#endif
}
template<int CTRL>
__device__ __forceinline__ float2 bfly_dpp(float2 z, float sg, float2 tw) {
    const float cx = dppx<CTRL>(z.x), cy = dppx<CTRL>(z.y);
    float ux = fmaf(sg, z.x, cx), uy = fmaf(sg, z.y, cy);
    return make_float2(ux*tw.x - uy*tw.y, ux*tw.y + uy*tw.x);
}
__device__ __forceinline__ float2 bfly1_dpp(float2 z, float sg) {   // d=1, tw==1
    const float cx = dppx<0xB1>(z.x), cy = dppx<0xB1>(z.y);
    return make_float2(fmaf(sg, z.x, cx), fmaf(sg, z.y, cy));
}
// d=4: ds_swizzle BitMode xor4 = (4<<10)|0x1F = 0x101F (within 32-lane groups)
__device__ __forceinline__ float2 bfly_ds4(float2 z, float sg, float2 tw) {
    const float cx = __int_as_float(__builtin_amdgcn_ds_swizzle(__float_as_int(z.x), 0x101F));
    const float cy = __int_as_float(__builtin_amdgcn_ds_swizzle(__float_as_int(z.y), 0x101F));
    float ux = fmaf(sg, z.x, cx), uy = fmaf(sg, z.y, cy);
    return make_float2(ux*tw.x - uy*tw.y, ux*tw.y + uy*tw.x);
}

// Four independent 64-pt FFTs; natural lane order in, result at lane L is G[brev6(L)].
__device__ __forceinline__ void fft64x4(float2 z[4], const XT& T) {
    #pragma unroll
    for (int a = 0; a < 4; ++a) {
        z[a] = bfly_pl32(z[a], T.s32, T.t32);
        z[a] = bfly_pl16(z[a], T.s16, T.t16);
        z[a] = bfly_dpp<0x128>(z[a], T.s8, T.t8);
        z[a] = bfly_ds4(z[a], T.s4, T.t4);
        z[a] = bfly_dpp<0x4E>(z[a], T.s2, T.t2);
        z[a] = bfly1_dpp(z[a], T.s1);
    }
}
// Twiddle by W256^{a*brev(L)} then in-lane DFT4: X[q] = F[brev6(L) + 64q].
__device__ __forceinline__ void twdft4(const float2 z[4], const XT& T, float2 X[4]) {
    float2 g0 = z[0], g1 = cmul(z[1], T.w1), g2 = cmul(z[2], T.w2), g3 = cmul(z[3], T.w3);
    float2 b0 = {g0.x+g2.x, g0.y+g2.y}, b1 = {g0.x-g2.x, g0.y-g2.y};
    float2 b2 = {g1.x+g3.x, g1.y+g3.y}, b3 = {g1.x-g3.x, g1.y-g3.y};
    X[0] = {b0.x+b2.x, b0.y+b2.y};
    X[2] = {b0.x-b2.x, b0.y-b2.y};
    X[1] = {b1.x+b3.y, b1.y-b3.x};   // b1 - i*b3
    X[3] = {b1.x-b3.y, b1.y+b3.x};   // b1 + i*b3
}

// One 1024-thread workgroup per image. Row-pair FFTs (real-pack) -> half2 LDS
// tile [kx][y^(kx&28)] -> column FFTs -> |F|^2 -> prefix-scan binning -> loss.
__global__ __launch_bounds__(1024)
void k_fused(const float* __restrict__ pred, const int4* __restrict__ tbl,
             const int* __restrict__ cnt, const float* __restrict__ mean_cl,
             const float* __restrict__ weighting, float* __restrict__ out,
             float cscale, float invB64) {
    __shared__ __align__(16) unsigned tile[129 * 256];   // half2 as u32, 132096 B
    __shared__ __align__(16) float pbuf[16][260];        // per-wave scan buffer
    const int tid = threadIdx.x, w = tid >> 6, L = tid & 63;
    const int rL = brev6(L);
    const float PI2 = 6.283185307179586f;

    XT T;
    {
        float sg, cg;
        auto stw = [&](int d, float2& t, float& s) {
            s = (L & d) ? -1.f : 1.f;
            const int e = (L & d) ? (L & (d-1)) * (32/d) : 0;
            float ss, cc; __sincosf(-PI2 * (float)e / 64.f, &ss, &cc);
            t = make_float2(cc, ss);
        };
        stw(32, T.t32, T.s32); stw(16, T.t16, T.s16); stw(8, T.t8, T.s8);
        stw(4, T.t4, T.s4); stw(2, T.t2, T.s2);
        T.s1 = (L & 1) ? -1.f : 1.f;
        __sincosf(-PI2 * (float)rL / 256.f, &sg, &cg);
        T.w1 = make_float2(cg, sg);
        T.w2 = cmul(T.w1, T.w1);
        T.w3 = cmul(T.w2, T.w1);
        T.pl = brev6((64 - rL) & 63);
    }

    // ---------------- row phase: 8 row-pairs per wave ----------------
    const float* base = pred + (size_t)blockIdx.x * 65536;
    const int sw = rL & 28;
    #pragma unroll 2
    for (int t = 0; t < 8; ++t) {
        const int y = 16*w + 2*t;
        const float4 ra = *(const float4*)(base + (size_t)y*256 + 4*L);
        const float4 rb = *(const float4*)(base + (size_t)(y+1)*256 + 4*L);
        float2 z[4] = {{ra.x,rb.x},{ra.y,rb.y},{ra.z,rb.z},{ra.w,rb.w}};
        fft64x4(z, T);                  // z = packed-FFT Z at kx=brev(L)+64q
        float2 X[4]; twdft4(z, T, X);
        // Hermitian unpack partners: conj(Z[256-kx])
        float2 q0, q1;
        q0.x = __shfl(X[3].x, T.pl); q0.y = __shfl(X[3].y, T.pl);
        q1.x = __shfl(X[2].x, T.pl); q1.y = __shfl(X[2].y, T.pl);
        if (L == 0) { q0 = X[0]; q1 = X[3]; }   // kx=0 and kx=64 fixes
        const int yi = y ^ sw;                   // y even, sw low2=0 -> +1 ok
        {   // kx = rL:  F_y = 0.5(A+conj(q)),  F_{y+1} = -0.5i(A-conj(q))
            const float fx = 0.5f*(X[0].x + q0.x), fy = 0.5f*(X[0].y - q0.y);
            const float gx = 0.5f*(X[0].y + q0.y), gy = -0.5f*(X[0].x - q0.x);
            uint2 pk; pk.x = f2h(fx, fy); pk.y = f2h(gx, gy);
            *(uint2*)&tile[rL*256 + yi] = pk;
        }
        {   // kx = 64 + rL  (same swizzle: (64+rL)&28 == rL&28)
            const float fx = 0.5f*(X[1].x + q1.x), fy = 0.5f*(X[1].y - q1.y);
            const float gx = 0.5f*(X[1].y + q1.y), gy = -0.5f*(X[1].x - q1.x);
            uint2 pk; pk.x = f2h(fx, fy); pk.y = f2h(gx, gy);
            *(uint2*)&tile[(64+rL)*256 + yi] = pk;
        }
        if (L == 0) {   // kx = 128: Z[128] self-conjugate -> F=(Re, Im)
            uint2 pk; pk.x = f2h(X[2].x, 0.f); pk.y = f2h(X[2].y, 0.f);
            *(uint2*)&tile[128*256 + y] = pk;
        }
    }
    __syncthreads();

    // ---------------- column phase: kx = w + 16t ----------------
    float acc = 0.f;                   // lane accumulates bin (L+1)
    float* pb = pbuf[w];
    if (L == 0) pb[256] = 0.f;         // sentinel (float4 stores cover 0..255 only)
    #pragma unroll 1
    for (int kx = w; kx <= 128; kx += 16) {
        const int cs = kx & 28;
        const int4 tb = tbl[kx*64 + L];  // <=2 ky-runs as prefix indices (early issue)
        const uint4 uu = *(const uint4*)&tile[kx*256 + ((4*L) ^ cs)];
        float2 z[4] = { h2f(uu.x), h2f(uu.y), h2f(uu.z), h2f(uu.w) }; // x[4L+a]
        fft64x4(z, T);
        float2 X[4]; twdft4(z, T, X);  // X[q] = F[ky = brev(L) + 64q]
        pb[rL]       = X[0].x*X[0].x + X[0].y*X[0].y;   // natural-order scatter
        pb[rL + 64]  = X[1].x*X[1].x + X[1].y*X[1].y;
        pb[rL + 128] = X[2].x*X[2].x + X[2].y*X[2].y;
        pb[rL + 192] = X[3].x*X[3].x + X[3].y*X[3].y;
        const float4 pv = ((const float4*)pb)[L];
        const float s0 = pv.x, s1 = s0+pv.y, s2 = s1+pv.z, s3 = s2+pv.w;
        float x = s3;
        #pragma unroll
        for (int off = 1; off < 64; off <<= 1) {
            const float yv = __shfl_up(x, off);
            if (L >= off) x += yv;
        }
        const float ex = x - s3;       // exclusive prefix of the lane's 4-group
        ((float4*)pb)[L] = make_float4(ex+s0, ex+s1, ex+s2, ex+s3);
        const float csum = pb[tb.y] - pb[tb.x] + pb[tb.w] - pb[tb.z];
        const float symw = (kx == 0 || kx == 128) ? 1.f : 2.f;
        acc = fmaf(symw, csum, acc);
    }
    __syncthreads();

    // ---------------- reduce 16 waves, per-image loss ----------------
    float* bins = (float*)tile;        // tile dead now
    bins[w*64 + L] = acc;
    __syncthreads();
    if (tid < 64) {
        float tot = 0.f;
        #pragma unroll
        for (int ww = 0; ww < 16; ++ww) tot += bins[ww*64 + tid];
        const int c = cnt[tid + 1];
        const float inv = (c > 0) ? 1.0f / (float)c : 0.0f;
        const float v = tot * cscale * inv;
        const float d = logf(v + 1e-12f) - logf(mean_cl[tid] + 1e-12f);
        float l = weighting[tid] * d * d;
        #pragma unroll
        for (int o = 32; o; o >>= 1) l += __shfl_down(l, o);
        if (tid == 0) atomicAdd(out, l * invB64);
    }
}

// Prep: one block per kx row (0..255). All rows: per-segment counts (LDS hist
// -> global atomics). Rows 0..128 additionally emit the boundary table: per
// (kx, bin) the <=2 contiguous ky-runs (radius monotone for ky 0..128,
// mirrored above), as prefix-lookup indices; 256 = zero sentinel slot.
__global__ __launch_bounds__(256) void k_prep(const int* __restrict__ seg,
                                              int4* __restrict__ tbl,
                                              int* __restrict__ cnt) {
    __shared__ int lo1[NSEG], hi1[NSEG], lo2[NSEG], hi2[NSEG], lc[NSEG];
    const int kx = blockIdx.x, ky = threadIdx.x;
    if (ky < NSEG) { lo1[ky] = 300; hi1[ky] = -1; lo2[ky] = 300; hi2[ky] = -1; lc[ky] = 0; }
    __syncthreads();
    const int s = seg[kx * 256 + ky];
    atomicAdd(&lc[s], 1);
    if (kx <= 128) {
        if (ky <= 128) { atomicMin(&lo1[s], ky); atomicMax(&hi1[s], ky); }
        else           { atomicMin(&lo2[s], ky); atomicMax(&hi2[s], ky); }
    }
    __syncthreads();
    if (ky < NSEG && lc[ky] > 0) atomicAdd(&cnt[ky], lc[ky]);
    if (kx <= 128 && ky >= 1 && ky <= 64) {
        int4 t;
        if (hi1[ky] < 0) { t.x = 256; t.y = 256; }
        else             { t.x = (lo1[ky] > 0) ? lo1[ky] - 1 : 256; t.y = hi1[ky]; }
        if (hi2[ky] < 0) { t.z = 256; t.w = 256; }
        else             { t.z = lo2[ky] - 1; t.w = hi2[ky]; }
        tbl[kx * 64 + (ky - 1)] = t;
    }
}

extern "C" void kernel_launch(void* const* d_in, const int* in_sizes, int n_in,
                              void* d_out, int out_size, void* d_ws, size_t ws_size,
                              hipStream_t stream) {
    const float* pred      = (const float*)d_in[0];
    const float* mean_cl   = (const float*)d_in[1];
    const float* weighting = (const float*)d_in[2];
    const int*   seg       = (const int*)d_in[3];
    float* out = (float*)d_out;

    const int B = in_sizes[0] / 65536;

    // ws: [cnt 66 i32, pad to 256B][boundary table 129*64 int4]
    int*  cnt = (int*)d_ws;
    int4* tbl = (int4*)((char*)d_ws + 256);

    const double rad = (5.0 * 60.0 / 256.0) * M_PI / 180.0;
    const float cscale = (float)(rad * rad / (65536.0 * 1e12)); // rad^2/N^2/TSZ^2
    const float invB64 = (float)(1.0 / ((double)B * 64.0));

    hipMemsetAsync(d_out, 0, sizeof(float), stream);
    hipMemsetAsync(cnt, 0, NSEG * sizeof(int), stream);
    k_prep<<<256, 256, 0, stream>>>(seg, tbl, cnt);
    k_fused<<<B, 1024, 0, stream>>>(pred, tbl, cnt, mean_cl, weighting,
                                    out, cscale, invB64);
}

// Round 10
// 144.805 us; speedup vs baseline: 4.2971x; 1.1175x over previous
//
#include <hip/hip_runtime.h>
#include <hip/hip_fp16.h>
#include <math.h>

#define NSEG 66                 // segments 0..65; valid bins 1..64
typedef unsigned uv2 __attribute__((ext_vector_type(2)));
typedef float fx2 __attribute__((ext_vector_type(2)));   // (re, im) in a VGPR pair

__device__ __forceinline__ int brev6(int l) {
    return ((l&1)<<5)|((l&2)<<3)|((l&4)<<1)|((l&8)>>1)|((l&16)>>3)|((l&32)>>5);
}
__device__ __forceinline__ unsigned f2h(float a, float b) {
    __half2 h = __floats2half2_rn(a, b); return *reinterpret_cast<unsigned*>(&h);
}

// ---------------- packed fp32 primitives (VOP3P, full-rate on CDNA) ----------------
__device__ __forceinline__ fx2 pk_fma(fx2 a, fx2 b, fx2 c) {        // a*b + c
    fx2 d; asm("v_pk_fma_f32 %0, %1, %2, %3" : "=v"(d) : "v"(a), "v"(b), "v"(c));
    return d;
}
__device__ __forceinline__ fx2 pk_add(fx2 a, fx2 b) {
    fx2 d; asm("v_pk_add_f32 %0, %1, %2" : "=v"(d) : "v"(a), "v"(b));
    return d;
}
__device__ __forceinline__ fx2 pk_sub(fx2 a, fx2 b) {
    fx2 d; asm("v_pk_add_f32 %0, %1, %2 neg_lo:[0,1] neg_hi:[0,1]" : "=v"(d) : "v"(a), "v"(b));
    return d;
}
__device__ __forceinline__ fx2 pk_addmi(fx2 a, fx2 b) {  // a - i*b = (a.x+b.y, a.y-b.x)
    fx2 d; asm("v_pk_add_f32 %0, %1, %2 op_sel:[0,1] op_sel_hi:[1,0] neg_hi:[0,1]"
               : "=v"(d) : "v"(a), "v"(b));
    return d;
}
__device__ __forceinline__ fx2 pk_addpi(fx2 a, fx2 b) {  // a + i*b = (a.x-b.y, a.y+b.x)
    fx2 d; asm("v_pk_add_f32 %0, %1, %2 op_sel:[0,1] op_sel_hi:[1,0] neg_lo:[0,1]"
               : "=v"(d) : "v"(a), "v"(b));
    return d;
}
// complex mul: z=(x,y), ta=(twx,twy), tb=(-twy,twy) -> (x*twx - y*twy, x*twy + y*twx)
__device__ __forceinline__ fx2 cmul_pk(fx2 z, fx2 ta, fx2 tb) {
    fx2 p, r;
    // p = (x*twx, y*twx): src1 lo for both result halves
    asm("v_pk_mul_f32 %0, %1, %2 op_sel:[0,0] op_sel_hi:[1,0]" : "=v"(p) : "v"(z), "v"(ta));
    // r = (y*(-twy) + p.lo, x*(twy) + p.hi): src0 swapped via op_sel
    asm("v_pk_fma_f32 %0, %1, %2, %3 op_sel:[1,0,0] op_sel_hi:[0,1,1]"
        : "=v"(r) : "v"(z), "v"(tb), "v"(p));
    return r;
}

// Per-lane constants for the four-step 256-pt FFT (all in registers).
struct XT {
    fx2 ta32, tb32, sg32;   // per xor-stage: ta=(twx,twy), tb=(-twy,twy), sg=(s,s)
    fx2 ta16, tb16, sg16;
    fx2 ta8,  tb8,  sg8;
    fx2 ta4,  tb4,  sg4;
    fx2 ta2,  tb2,  sg2;
    fx2 sg1;
    fx2 wa1, wb1, wa2, wb2, wa3, wb3;  // W256^{brev(L)},^2,^3 as (ta,tb) pairs
    int pl;                            // Hermitian partner lane
};

// ---- cross-lane exchange + packed butterfly (u = ret0 + sg*ret1, then *tw) ----
__device__ __forceinline__ fx2 bfly_pl32(fx2 z, fx2 sg, fx2 ta, fx2 tb) {
#if __has_builtin(__builtin_amdgcn_permlane32_swap)
    uv2 rx = __builtin_amdgcn_permlane32_swap(__float_as_uint(z[0]), __float_as_uint(z[0]), false, false);
    uv2 ry = __builtin_amdgcn_permlane32_swap(__float_as_uint(z[1]), __float_as_uint(z[1]), false, false);
    fx2 r0 = {__uint_as_float(rx[0]), __uint_as_float(ry[0])};
    fx2 r1 = {__uint_as_float(rx[1]), __uint_as_float(ry[1])};
    fx2 u = pk_fma(r1, sg, r0);
#else
    fx2 c = {__shfl_xor(z[0], 32), __shfl_xor(z[1], 32)};
    fx2 u = pk_fma(z, sg, c);
#endif
    return cmul_pk(u, ta, tb);
}
__device__ __forceinline__ fx2 bfly_pl16(fx2 z, fx2 sg, fx2 ta, fx2 tb) {
#if __has_builtin(__builtin_amdgcn_permlane16_swap)
    uv2 rx = __builtin_amdgcn_permlane16_swap(__float_as_uint(z[0]), __float_as_uint(z[0]), false, false);
    uv2 ry = __builtin_amdgcn_permlane16_swap(__float_as_uint(z[1]), __float_as_uint(z[1]), false, false);
    fx2 r0 = {__uint_as_float(rx[0]), __uint_as_float(ry[0])};
    fx2 r1 = {__uint_as_float(rx[1]), __uint_as_float(ry[1])};
    fx2 u = pk_fma(r1, sg, r0);
#else
    fx2 c = {__shfl_xor(z[0], 16), __shfl_xor(z[1], 16)};
    fx2 u = pk_fma(z, sg, c);
#endif
    return cmul_pk(u, ta, tb);
}
// DPP xor-permutes: row_ror:8 (0x128) = xor8; quad_perm 0x4E = xor2; 0xB1 = xor1
template<int CTRL>
__device__ __forceinline__ float dppx(float x) {
#if __has_builtin(__builtin_amdgcn_update_dpp)
    return __int_as_float(__builtin_amdgcn_update_dpp(
        __float_as_int(x), __float_as_int(x), CTRL, 0xF, 0xF, false));
#else
    const int d = (CTRL == 0x128) ? 8 : (CTRL == 0x4E ? 2 : 1);
    return __shfl_xor(x, d);
#endif
}
template<int CTRL>
__device__ __forceinline__ fx2 bfly_dpp(fx2 z, fx2 sg, fx2 ta, fx2 tb) {
    fx2 c = {dppx<CTRL>(z[0]), dppx<CTRL>(z[1])};
    return cmul_pk(pk_fma(z, sg, c), ta, tb);
}
__device__ __forceinline__ fx2 bfly1_dpp(fx2 z, fx2 sg) {   // d=1, tw==1
    fx2 c = {dppx<0xB1>(z[0]), dppx<0xB1>(z[1])};
    return pk_fma(z, sg, c);
}
// d=4: ds_swizzle BitMode xor4 = 0x101F
__device__ __forceinline__ fx2 bfly_ds4(fx2 z, fx2 sg, fx2 ta, fx2 tb) {
    fx2 c = {__int_as_float(__builtin_amdgcn_ds_swizzle(__float_as_int(z[0]), 0x101F)),
             __int_as_float(__builtin_amdgcn_ds_swizzle(__float_as_int(z[1]), 0x101F))};
    return cmul_pk(pk_fma(z, sg, c), ta, tb);
}

// Four independent 64-pt FFTs; natural lane order in, result at lane L is G[brev6(L)].
__device__ __forceinline__ void fft64x4(fx2 z[4], const XT& T) {
    #pragma unroll
    for (int a = 0; a < 4; ++a) {
        z[a] = bfly_pl32(z[a], T.sg32, T.ta32, T.tb32);
        z[a] = bfly_pl16(z[a], T.sg16, T.ta16, T.tb16);
        z[a] = bfly_dpp<0x128>(z[a], T.sg8, T.ta8, T.tb8);
        z[a] = bfly_ds4(z[a], T.sg4, T.ta4, T.tb4);
        z[a] = bfly_dpp<0x4E>(z[a], T.sg2, T.ta2, T.tb2);
        z[a] = bfly1_dpp(z[a], T.sg1);
    }
}
// Twiddle by W256^{a*brev(L)} then in-lane DFT4: X[q] = F[brev6(L) + 64q].
__device__ __forceinline__ void twdft4(const fx2 z[4], const XT& T, fx2 X[4]) {
    fx2 g0 = z[0];
    fx2 g1 = cmul_pk(z[1], T.wa1, T.wb1);
    fx2 g2 = cmul_pk(z[2], T.wa2, T.wb2);
    fx2 g3 = cmul_pk(z[3], T.wa3, T.wb3);
    fx2 b0 = pk_add(g0, g2), b1 = pk_sub(g0, g2);
    fx2 b2 = pk_add(g1, g3), b3 = pk_sub(g1, g3);
    X[0] = pk_add(b0, b2);
    X[2] = pk_sub(b0, b2);
    X[1] = pk_addmi(b1, b3);   // b1 - i*b3
    X[3] = pk_addpi(b1, b3);   // b1 + i*b3
}

// One 1024-thread workgroup per image. Row-pair FFTs (real-pack) -> half2 LDS
// tile [kx][y^(kx&28)] -> column FFTs -> |F|^2 -> prefix-scan binning -> loss.
__global__ __launch_bounds__(1024)
void k_fused(const float* __restrict__ pred, const int4* __restrict__ tbl,
             const int* __restrict__ cnt, const float* __restrict__ mean_cl,
             const float* __restrict__ weighting, float* __restrict__ out,
             float cscale, float invB64) {
    __shared__ __align__(16) unsigned tile[129 * 256];   // half2 as u32, 132096 B
    __shared__ __align__(16) float pbuf[16][260];        // per-wave scan buffer
    const int tid = threadIdx.x, w = tid >> 6, L = tid & 63;
    const int rL = brev6(L);
    const float PI2 = 6.283185307179586f;

    XT T;
    {
        auto stw = [&](int d, fx2& ta, fx2& tb, fx2& sg) {
            const float s = (L & d) ? -1.f : 1.f;
            const int e = (L & d) ? (L & (d-1)) * (32/d) : 0;
            float ss, cc; __sincosf(-PI2 * (float)e / 64.f, &ss, &cc);
            ta[0] = cc; ta[1] = ss; tb[0] = -ss; tb[1] = ss; sg[0] = s; sg[1] = s;
        };
        stw(32, T.ta32, T.tb32, T.sg32);
        stw(16, T.ta16, T.tb16, T.sg16);
        stw( 8, T.ta8,  T.tb8,  T.sg8);
        stw( 4, T.ta4,  T.tb4,  T.sg4);
        stw( 2, T.ta2,  T.tb2,  T.sg2);
        const float s1 = (L & 1) ? -1.f : 1.f;
        T.sg1[0] = s1; T.sg1[1] = s1;
        float sg, cg;
        __sincosf(-PI2 * (float)rL / 256.f, &sg, &cg);
        const float w2x = cg*cg - sg*sg, w2y = 2.f*cg*sg;
        const float w3x = w2x*cg - w2y*sg, w3y = w2x*sg + w2y*cg;
        T.wa1[0] = cg;  T.wa1[1] = sg;  T.wb1[0] = -sg;  T.wb1[1] = sg;
        T.wa2[0] = w2x; T.wa2[1] = w2y; T.wb2[0] = -w2y; T.wb2[1] = w2y;
        T.wa3[0] = w3x; T.wa3[1] = w3y; T.wb3[0] = -w3y; T.wb3[1] = w3y;
        T.pl = brev6((64 - rL) & 63);
    }

    // ---------------- row phase: 8 row-pairs per wave ----------------
    const float* base = pred + (size_t)blockIdx.x * 65536;
    const int sw = rL & 28;
    #pragma unroll 2
    for (int t = 0; t < 8; ++t) {
        const int y = 16*w + 2*t;
        const float4 ra = *(const float4*)(base + (size_t)y*256 + 4*L);
        const float4 rb = *(const float4*)(base + (size_t)(y+1)*256 + 4*L);
        fx2 z[4] = {{ra.x,rb.x},{ra.y,rb.y},{ra.z,rb.z},{ra.w,rb.w}};
        fft64x4(z, T);                  // z = packed-FFT Z at kx=brev(L)+64q
        fx2 X[4]; twdft4(z, T, X);
        // Hermitian unpack partners: conj(Z[256-kx])
        float q0x = __shfl(X[3][0], T.pl), q0y = __shfl(X[3][1], T.pl);
        float q1x = __shfl(X[2][0], T.pl), q1y = __shfl(X[2][1], T.pl);
        if (L == 0) { q0x = X[0][0]; q0y = X[0][1]; q1x = X[3][0]; q1y = X[3][1]; }
        const int yi = y ^ sw;                   // y even, sw low2=0 -> +1 ok
        {   // kx = rL:  F_y = 0.5(A+conj(q)),  F_{y+1} = -0.5i(A-conj(q))
            const float fx = 0.5f*(X[0][0] + q0x), fy = 0.5f*(X[0][1] - q0y);
            const float gx = 0.5f*(X[0][1] + q0y), gy = -0.5f*(X[0][0] - q0x);
            uint2 pk; pk.x = f2h(fx, fy); pk.y = f2h(gx, gy);
            *(uint2*)&tile[rL*256 + yi] = pk;
        }
        {   // kx = 64 + rL  (same swizzle: (64+rL)&28 == rL&28)
            const float fx = 0.5f*(X[1][0] + q1x), fy = 0.5f*(X[1][1] - q1y);
            const float gx = 0.5f*(X[1][1] + q1y), gy = -0.5f*(X[1][0] - q1x);
            uint2 pk; pk.x = f2h(fx, fy); pk.y = f2h(gx, gy);
            *(uint2*)&tile[(64+rL)*256 + yi] = pk;
        }
        if (L == 0) {   // kx = 128: Z[128] self-conjugate -> F=(Re, Im)
            uint2 pk; pk.x = f2h(X[2][0], 0.f); pk.y = f2h(X[2][1], 0.f);
            *(uint2*)&tile[128*256 + y] = pk;
        }
    }
    __syncthreads();

    // ---------------- column phase: kx = w + 16t ----------------
    float acc = 0.f;                   // lane accumulates bin (L+1)
    float* pb = pbuf[w];
    if (L == 0) pb[256] = 0.f;         // sentinel (float4 stores cover 0..255 only)
    #pragma unroll 1
    for (int kx = w; kx <= 128; kx += 16) {
        const int cs = kx & 28;
        const int4 tb = tbl[kx*64 + L];  // <=2 ky-runs as prefix indices (early issue)
        const uint4 uu = *(const uint4*)&tile[kx*256 + ((4*L) ^ cs)];
        fx2 z[4];
        {
            const float2 v0 = __half22float2(*(const __half2*)&uu.x);
            const float2 v1 = __half22float2(*(const __half2*)&uu.y);
            const float2 v2 = __half22float2(*(const __half2*)&uu.z);
            const float2 v3 = __half22float2(*(const __half2*)&uu.w);
            z[0][0]=v0.x; z[0][1]=v0.y; z[1][0]=v1.x; z[1][1]=v1.y;
            z[2][0]=v2.x; z[2][1]=v2.y; z[3][0]=v3.x; z[3][1]=v3.y;
        }
        fft64x4(z, T);
        fx2 X[4]; twdft4(z, T, X);     // X[q] = F[ky = brev(L) + 64q]
        pb[rL]       = X[0][0]*X[0][0] + X[0][1]*X[0][1];   // natural-order scatter
        pb[rL + 64]  = X[1][0]*X[1][0] + X[1][1]*X[1][1];
        pb[rL + 128] = X[2][0]*X[2][0] + X[2][1]*X[2][1];
        pb[rL + 192] = X[3][0]*X[3][0] + X[3][1]*X[3][1];
        const float4 pv = ((const float4*)pb)[L];
        const float s0 = pv.x, s1 = s0+pv.y, s2 = s1+pv.z, s3 = s2+pv.w;
        float x = s3;
        #pragma unroll
        for (int off = 1; off < 64; off <<= 1) {
            const float yv = __shfl_up(x, off);
            if (L >= off) x += yv;
        }
        const float ex = x - s3;       // exclusive prefix of the lane's 4-group
        ((float4*)pb)[L] = make_float4(ex+s0, ex+s1, ex+s2, ex+s3);
        const float csum = pb[tb.y] - pb[tb.x] + pb[tb.w] - pb[tb.z];
        const float symw = (kx == 0 || kx == 128) ? 1.f : 2.f;
        acc = fmaf(symw, csum, acc);
    }
    __syncthreads();

    // ---------------- reduce 16 waves, per-image loss ----------------
    float* bins = (float*)tile;        // tile dead now
    bins[w*64 + L] = acc;
    __syncthreads();
    if (tid < 64) {
        float tot = 0.f;
        #pragma unroll
        for (int ww = 0; ww < 16; ++ww) tot += bins[ww*64 + tid];
        const int c = cnt[tid + 1];
        const float inv = (c > 0) ? 1.0f / (float)c : 0.0f;
        const float v = tot * cscale * inv;
        const float d = logf(v + 1e-12f) - logf(mean_cl[tid] + 1e-12f);
        float l = weighting[tid] * d * d;
        #pragma unroll
        for (int o = 32; o; o >>= 1) l += __shfl_down(l, o);
        if (tid == 0) atomicAdd(out, l * invB64);
    }
}

// Prep: one block per kx row (0..255). All rows: per-segment counts (LDS hist
// -> global atomics). Rows 0..128 additionally emit the boundary table: per
// (kx, bin) the <=2 contiguous ky-runs (radius monotone for ky 0..128,
// mirrored above), as prefix-lookup indices; 256 = zero sentinel slot.
__global__ __launch_bounds__(256) void k_prep(const int* __restrict__ seg,
                                              int4* __restrict__ tbl,
                                              int* __restrict__ cnt) {
    __shared__ int lo1[NSEG], hi1[NSEG], lo2[NSEG], hi2[NSEG], lc[NSEG];
    const int kx = blockIdx.x, ky = threadIdx.x;
    if (ky < NSEG) { lo1[ky] = 300; hi1[ky] = -1; lo2[ky] = 300; hi2[ky] = -1; lc[ky] = 0; }
    __syncthreads();
    const int s = seg[kx * 256 + ky];
    atomicAdd(&lc[s], 1);
    if (kx <= 128) {
        if (ky <= 128) { atomicMin(&lo1[s], ky); atomicMax(&hi1[s], ky); }
        else           { atomicMin(&lo2[s], ky); atomicMax(&hi2[s], ky); }
    }
    __syncthreads();
    if (ky < NSEG && lc[ky] > 0) atomicAdd(&cnt[ky], lc[ky]);
    if (kx <= 128 && ky >= 1 && ky <= 64) {
        int4 t;
        if (hi1[ky] < 0) { t.x = 256; t.y = 256; }
        else             { t.x = (lo1[ky] > 0) ? lo1[ky] - 1 : 256; t.y = hi1[ky]; }
        if (hi2[ky] < 0) { t.z = 256; t.w = 256; }
        else             { t.z = lo2[ky] - 1; t.w = hi2[ky]; }
        tbl[kx * 64 + (ky - 1)] = t;
    }
}

extern "C" void kernel_launch(void* const* d_in, const int* in_sizes, int n_in,
                              void* d_out, int out_size, void* d_ws, size_t ws_size,
                              hipStream_t stream) {
    const float* pred      = (const float*)d_in[0];
    const float* mean_cl   = (const float*)d_in[1];
    const float* weighting = (const float*)d_in[2];
    const int*   seg       = (const int*)d_in[3];
    float* out = (float*)d_out;

    const int B = in_sizes[0] / 65536;

    // ws: [cnt 66 i32, pad to 256B][boundary table 129*64 int4]
    int*  cnt = (int*)d_ws;
    int4* tbl = (int4*)((char*)d_ws + 256);

    const double rad = (5.0 * 60.0 / 256.0) * M_PI / 180.0;
    const float cscale = (float)(rad * rad / (65536.0 * 1e12)); // rad^2/N^2/TSZ^2
    const float invB64 = (float)(1.0 / ((double)B * 64.0));

    hipMemsetAsync(d_out, 0, sizeof(float), stream);
    hipMemsetAsync(cnt, 0, NSEG * sizeof(int), stream);
    k_prep<<<256, 256, 0, stream>>>(seg, tbl, cnt);
    k_fused<<<B, 1024, 0, stream>>>(pred, tbl, cnt, mean_cl, weighting,
                                    out, cscale, invB64);
}

// Round 11
// 143.618 us; speedup vs baseline: 4.3326x; 1.0083x over previous
//
#include <hip/hip_runtime.h>
#include <hip/hip_fp16.h>
#include <math.h>

#define NSEG 66                 // segments 0..65; valid bins 1..64
typedef unsigned uv2 __attribute__((ext_vector_type(2)));
typedef float fx2 __attribute__((ext_vector_type(2)));   // (re, im) in a VGPR pair

__device__ __forceinline__ int brev6(int l) {
    return ((l&1)<<5)|((l&2)<<3)|((l&4)<<1)|((l&8)>>1)|((l&16)>>3)|((l&32)>>5);
}
__device__ __forceinline__ unsigned f2h(float a, float b) {
    __half2 h = __floats2half2_rn(a, b); return *reinterpret_cast<unsigned*>(&h);
}

// ---------------- packed fp32 primitives (VOP3P, full-rate on CDNA) ----------------
__device__ __forceinline__ fx2 pk_fma(fx2 a, fx2 b, fx2 c) {        // a*b + c
    fx2 d; asm("v_pk_fma_f32 %0, %1, %2, %3" : "=v"(d) : "v"(a), "v"(b), "v"(c));
    return d;
}
__device__ __forceinline__ fx2 pk_add(fx2 a, fx2 b) {
    fx2 d; asm("v_pk_add_f32 %0, %1, %2" : "=v"(d) : "v"(a), "v"(b));
    return d;
}
__device__ __forceinline__ fx2 pk_sub(fx2 a, fx2 b) {
    fx2 d; asm("v_pk_add_f32 %0, %1, %2 neg_lo:[0,1] neg_hi:[0,1]" : "=v"(d) : "v"(a), "v"(b));
    return d;
}
__device__ __forceinline__ fx2 pk_addmi(fx2 a, fx2 b) {  // a - i*b = (a.x+b.y, a.y-b.x)
    fx2 d; asm("v_pk_add_f32 %0, %1, %2 op_sel:[0,1] op_sel_hi:[1,0] neg_hi:[0,1]"
               : "=v"(d) : "v"(a), "v"(b));
    return d;
}
__device__ __forceinline__ fx2 pk_addpi(fx2 a, fx2 b) {  // a + i*b = (a.x-b.y, a.y+b.x)
    fx2 d; asm("v_pk_add_f32 %0, %1, %2 op_sel:[0,1] op_sel_hi:[1,0] neg_lo:[0,1]"
               : "=v"(d) : "v"(a), "v"(b));
    return d;
}
// complex mul: z=(x,y), ta=(twx,twy), tb=(-twy,twy) -> (x*twx - y*twy, x*twy + y*twx)
__device__ __forceinline__ fx2 cmul_pk(fx2 z, fx2 ta, fx2 tb) {
    fx2 p, r;
    asm("v_pk_mul_f32 %0, %1, %2 op_sel:[0,0] op_sel_hi:[1,0]" : "=v"(p) : "v"(z), "v"(ta));
    asm("v_pk_fma_f32 %0, %1, %2, %3 op_sel:[1,0,0] op_sel_hi:[0,1,1]"
        : "=v"(r) : "v"(z), "v"(tb), "v"(p));
    return r;
}

// Per-lane constants for the four-step 256-pt FFT (all in registers).
struct XT {
    fx2 ta32, tb32, sg32;   // per xor-stage: ta=(twx,twy), tb=(-twy,twy), sg=(s,s)
    fx2 ta16, tb16, sg16;
    fx2 ta8,  tb8,  sg8;
    fx2 ta4,  tb4,  sg4;
    fx2 ta2,  tb2,  sg2;
    fx2 sg1;
    fx2 wa1, wb1, wa2, wb2, wa3, wb3;  // W256^{brev(L)},^2,^3 as (ta,tb) pairs
    int pl;                            // Hermitian partner lane
};

// ---- cross-lane exchange + packed butterfly (u = ret0 + sg*ret1, then *tw) ----
__device__ __forceinline__ fx2 bfly_pl32(fx2 z, fx2 sg, fx2 ta, fx2 tb) {
#if __has_builtin(__builtin_amdgcn_permlane32_swap)
    uv2 rx = __builtin_amdgcn_permlane32_swap(__float_as_uint(z[0]), __float_as_uint(z[0]), false, false);
    uv2 ry = __builtin_amdgcn_permlane32_swap(__float_as_uint(z[1]), __float_as_uint(z[1]), false, false);
    fx2 r0 = {__uint_as_float(rx[0]), __uint_as_float(ry[0])};
    fx2 r1 = {__uint_as_float(rx[1]), __uint_as_float(ry[1])};
    fx2 u = pk_fma(r1, sg, r0);
#else
    fx2 c = {__shfl_xor(z[0], 32), __shfl_xor(z[1], 32)};
    fx2 u = pk_fma(z, sg, c);
#endif
    return cmul_pk(u, ta, tb);
}
__device__ __forceinline__ fx2 bfly_pl16(fx2 z, fx2 sg, fx2 ta, fx2 tb) {
#if __has_builtin(__builtin_amdgcn_permlane16_swap)
    uv2 rx = __builtin_amdgcn_permlane16_swap(__float_as_uint(z[0]), __float_as_uint(z[0]), false, false);
    uv2 ry = __builtin_amdgcn_permlane16_swap(__float_as_uint(z[1]), __float_as_uint(z[1]), false, false);
    fx2 r0 = {__uint_as_float(rx[0]), __uint_as_float(ry[0])};
    fx2 r1 = {__uint_as_float(rx[1]), __uint_as_float(ry[1])};
    fx2 u = pk_fma(r1, sg, r0);
#else
    fx2 c = {__shfl_xor(z[0], 16), __shfl_xor(z[1], 16)};
    fx2 u = pk_fma(z, sg, c);
#endif
    return cmul_pk(u, ta, tb);
}
// DPP xor-permutes: row_ror:8 (0x128) = xor8; quad_perm 0x4E = xor2; 0xB1 = xor1
template<int CTRL>
__device__ __forceinline__ float dppx(float x) {
#if __has_builtin(__builtin_amdgcn_update_dpp)
    return __int_as_float(__builtin_amdgcn_update_dpp(
        __float_as_int(x), __float_as_int(x), CTRL, 0xF, 0xF, false));
#else
    const int d = (CTRL == 0x128) ? 8 : (CTRL == 0x4E ? 2 : 1);
    return __shfl_xor(x, d);
#endif
}
template<int CTRL>
__device__ __forceinline__ fx2 bfly_dpp(fx2 z, fx2 sg, fx2 ta, fx2 tb) {
    fx2 c = {dppx<CTRL>(z[0]), dppx<CTRL>(z[1])};
    return cmul_pk(pk_fma(z, sg, c), ta, tb);
}
__device__ __forceinline__ fx2 bfly1_dpp(fx2 z, fx2 sg) {   // d=1, tw==1
    fx2 c = {dppx<0xB1>(z[0]), dppx<0xB1>(z[1])};
    return pk_fma(z, sg, c);
}
// d=4: ds_swizzle BitMode xor4 = 0x101F
__device__ __forceinline__ fx2 bfly_ds4(fx2 z, fx2 sg, fx2 ta, fx2 tb) {
    fx2 c = {__int_as_float(__builtin_amdgcn_ds_swizzle(__float_as_int(z[0]), 0x101F)),
             __int_as_float(__builtin_amdgcn_ds_swizzle(__float_as_int(z[1]), 0x101F))};
    return cmul_pk(pk_fma(z, sg, c), ta, tb);
}

// 64-lane inclusive prefix sum on the VALU: classic GCN DPP scan.
// row_shr:1/2/4/8 (within 16-rows) then row_bcast:15 (rows 1,3) + row_bcast:31 (rows 2,3).
__device__ __forceinline__ float dpp_scan64(float x, int L) {
#if __has_builtin(__builtin_amdgcn_update_dpp)
    #define UPD(ctrl, rmask) __int_as_float(__builtin_amdgcn_update_dpp( \
        0, __float_as_int(x), ctrl, rmask, 0xF, false))
    x += UPD(0x111, 0xF);   // row_shr:1
    x += UPD(0x112, 0xF);   // row_shr:2
    x += UPD(0x114, 0xF);   // row_shr:4
    x += UPD(0x118, 0xF);   // row_shr:8
    x += UPD(0x142, 0xA);   // row_bcast:15 -> rows 1,3
    x += UPD(0x143, 0xC);   // row_bcast:31 -> rows 2,3
    #undef UPD
    return x;
#else
    #pragma unroll
    for (int off = 1; off < 64; off <<= 1) {
        const float yv = __shfl_up(x, off);
        if (L >= off) x += yv;
    }
    return x;
#endif
}

// Four independent 64-pt FFTs; natural lane order in, result at lane L is G[brev6(L)].
__device__ __forceinline__ void fft64x4(fx2 z[4], const XT& T) {
    #pragma unroll
    for (int a = 0; a < 4; ++a) {
        z[a] = bfly_pl32(z[a], T.sg32, T.ta32, T.tb32);
        z[a] = bfly_pl16(z[a], T.sg16, T.ta16, T.tb16);
        z[a] = bfly_dpp<0x128>(z[a], T.sg8, T.ta8, T.tb8);
        z[a] = bfly_ds4(z[a], T.sg4, T.ta4, T.tb4);
        z[a] = bfly_dpp<0x4E>(z[a], T.sg2, T.ta2, T.tb2);
        z[a] = bfly1_dpp(z[a], T.sg1);
    }
}
// Twiddle by W256^{a*brev(L)} then in-lane DFT4: X[q] = F[brev6(L) + 64q].
__device__ __forceinline__ void twdft4(const fx2 z[4], const XT& T, fx2 X[4]) {
    fx2 g0 = z[0];
    fx2 g1 = cmul_pk(z[1], T.wa1, T.wb1);
    fx2 g2 = cmul_pk(z[2], T.wa2, T.wb2);
    fx2 g3 = cmul_pk(z[3], T.wa3, T.wb3);
    fx2 b0 = pk_add(g0, g2), b1 = pk_sub(g0, g2);
    fx2 b2 = pk_add(g1, g3), b3 = pk_sub(g1, g3);
    X[0] = pk_add(b0, b2);
    X[2] = pk_sub(b0, b2);
    X[1] = pk_addmi(b1, b3);   // b1 - i*b3
    X[3] = pk_addpi(b1, b3);   // b1 + i*b3
}

// One 1024-thread workgroup per image. Row-pair FFTs (real-pack) -> half2 LDS
// tile [kx][y^(kx&28)] -> column FFTs -> |F|^2 -> prefix-scan binning -> loss.
__global__ __launch_bounds__(1024)
void k_fused(const float* __restrict__ pred, const int4* __restrict__ tbl,
             const int* __restrict__ cnt, const float* __restrict__ mean_cl,
             const float* __restrict__ weighting, float* __restrict__ out,
             float cscale, float invB64) {
    __shared__ __align__(16) unsigned tile[129 * 256];   // half2 as u32, 132096 B
    __shared__ __align__(16) float pbuf[16][260];        // per-wave scan buffer
    const int tid = threadIdx.x, w = tid >> 6, L = tid & 63;
    const int rL = brev6(L);
    const float PI2 = 6.283185307179586f;

    XT T;
    {
        auto stw = [&](int d, fx2& ta, fx2& tb, fx2& sg) {
            const float s = (L & d) ? -1.f : 1.f;
            const int e = (L & d) ? (L & (d-1)) * (32/d) : 0;
            float ss, cc; __sincosf(-PI2 * (float)e / 64.f, &ss, &cc);
            ta[0] = cc; ta[1] = ss; tb[0] = -ss; tb[1] = ss; sg[0] = s; sg[1] = s;
        };
        stw(32, T.ta32, T.tb32, T.sg32);
        stw(16, T.ta16, T.tb16, T.sg16);
        stw( 8, T.ta8,  T.tb8,  T.sg8);
        stw( 4, T.ta4,  T.tb4,  T.sg4);
        stw( 2, T.ta2,  T.tb2,  T.sg2);
        const float s1 = (L & 1) ? -1.f : 1.f;
        T.sg1[0] = s1; T.sg1[1] = s1;
        float sg, cg;
        __sincosf(-PI2 * (float)rL / 256.f, &sg, &cg);
        const float w2x = cg*cg - sg*sg, w2y = 2.f*cg*sg;
        const float w3x = w2x*cg - w2y*sg, w3y = w2x*sg + w2y*cg;
        T.wa1[0] = cg;  T.wa1[1] = sg;  T.wb1[0] = -sg;  T.wb1[1] = sg;
        T.wa2[0] = w2x; T.wa2[1] = w2y; T.wb2[0] = -w2y; T.wb2[1] = w2y;
        T.wa3[0] = w3x; T.wa3[1] = w3y; T.wb3[0] = -w3y; T.wb3[1] = w3y;
        T.pl = brev6((64 - rL) & 63);
    }

    // ---------------- row phase: 8 row-pairs per wave ----------------
    const float* base = pred + (size_t)blockIdx.x * 65536;
    const int sw = rL & 28;
    #pragma unroll 2
    for (int t = 0; t < 8; ++t) {
        const int y = 16*w + 2*t;
        const float4 ra = *(const float4*)(base + (size_t)y*256 + 4*L);
        const float4 rb = *(const float4*)(base + (size_t)(y+1)*256 + 4*L);
        fx2 z[4] = {{ra.x,rb.x},{ra.y,rb.y},{ra.z,rb.z},{ra.w,rb.w}};
        fft64x4(z, T);                  // z = packed-FFT Z at kx=brev(L)+64q
        fx2 X[4]; twdft4(z, T, X);
        // Hermitian unpack partners: conj(Z[256-kx])
        float q0x = __shfl(X[3][0], T.pl), q0y = __shfl(X[3][1], T.pl);
        float q1x = __shfl(X[2][0], T.pl), q1y = __shfl(X[2][1], T.pl);
        if (L == 0) { q0x = X[0][0]; q0y = X[0][1]; q1x = X[3][0]; q1y = X[3][1]; }
        const int yi = y ^ sw;                   // y even, sw low2=0 -> +1 ok
        {   // kx = rL:  F_y = 0.5(A+conj(q)),  F_{y+1} = -0.5i(A-conj(q))
            const float fx = 0.5f*(X[0][0] + q0x), fy = 0.5f*(X[0][1] - q0y);
            const float gx = 0.5f*(X[0][1] + q0y), gy = -0.5f*(X[0][0] - q0x);
            uint2 pk; pk.x = f2h(fx, fy); pk.y = f2h(gx, gy);
            *(uint2*)&tile[rL*256 + yi] = pk;
        }
        {   // kx = 64 + rL  (same swizzle: (64+rL)&28 == rL&28)
            const float fx = 0.5f*(X[1][0] + q1x), fy = 0.5f*(X[1][1] - q1y);
            const float gx = 0.5f*(X[1][1] + q1y), gy = -0.5f*(X[1][0] - q1x);
            uint2 pk; pk.x = f2h(fx, fy); pk.y = f2h(gx, gy);
            *(uint2*)&tile[(64+rL)*256 + yi] = pk;
        }
        if (L == 0) {   // kx = 128: Z[128] self-conjugate -> F=(Re, Im)
            uint2 pk; pk.x = f2h(X[2][0], 0.f); pk.y = f2h(X[2][1], 0.f);
            *(uint2*)&tile[128*256 + y] = pk;
        }
    }
    __syncthreads();

    // ---------------- column phase: kx = w + 16t ----------------
    float acc = 0.f;                   // lane accumulates bin (L+1)
    float* pb = pbuf[w];
    if (L == 0) pb[256] = 0.f;         // sentinel (float4 stores cover 0..255 only)
    #pragma unroll 2
    for (int kx = w; kx <= 128; kx += 16) {
        const int cs = kx & 28;
        const int4 tb = tbl[kx*64 + L];  // <=2 ky-runs as prefix indices (early issue)
        const uint4 uu = *(const uint4*)&tile[kx*256 + ((4*L) ^ cs)];
        fx2 z[4];
        {
            const float2 v0 = __half22float2(*(const __half2*)&uu.x);
            const float2 v1 = __half22float2(*(const __half2*)&uu.y);
            const float2 v2 = __half22float2(*(const __half2*)&uu.z);
            const float2 v3 = __half22float2(*(const __half2*)&uu.w);
            z[0][0]=v0.x; z[0][1]=v0.y; z[1][0]=v1.x; z[1][1]=v1.y;
            z[2][0]=v2.x; z[2][1]=v2.y; z[3][0]=v3.x; z[3][1]=v3.y;
        }
        fft64x4(z, T);
        fx2 X[4]; twdft4(z, T, X);     // X[q] = F[ky = brev(L) + 64q]
        pb[rL]       = X[0][0]*X[0][0] + X[0][1]*X[0][1];   // natural-order scatter
        pb[rL + 64]  = X[1][0]*X[1][0] + X[1][1]*X[1][1];
        pb[rL + 128] = X[2][0]*X[2][0] + X[2][1]*X[2][1];
        pb[rL + 192] = X[3][0]*X[3][0] + X[3][1]*X[3][1];
        const float4 pv = ((const float4*)pb)[L];
        const float s0 = pv.x, s1 = s0+pv.y, s2 = s1+pv.z, s3 = s2+pv.w;
        const float x = dpp_scan64(s3, L);          // inclusive scan of lane totals
        const float ex = x - s3;       // exclusive prefix of the lane's 4-group
        ((float4*)pb)[L] = make_float4(ex+s0, ex+s1, ex+s2, ex+s3);
        const float csum = pb[tb.y] - pb[tb.x] + pb[tb.w] - pb[tb.z];
        const float symw = (kx == 0 || kx == 128) ? 1.f : 2.f;
        acc = fmaf(symw, csum, acc);
    }
    __syncthreads();

    // ---------------- reduce 16 waves, per-image loss ----------------
    float* bins = (float*)tile;        // tile dead now
    bins[w*64 + L] = acc;
    __syncthreads();
    if (tid < 64) {
        float tot = 0.f;
        #pragma unroll
        for (int ww = 0; ww < 16; ++ww) tot += bins[ww*64 + tid];
        const int c = cnt[tid + 1];
        const float inv = (c > 0) ? 1.0f / (float)c : 0.0f;
        const float v = tot * cscale * inv;
        const float d = logf(v + 1e-12f) - logf(mean_cl[tid] + 1e-12f);
        float l = weighting[tid] * d * d;
        #pragma unroll
        for (int o = 32; o; o >>= 1) l += __shfl_down(l, o);
        if (tid == 0) atomicAdd(out, l * invB64);
    }
}

// Prep: one block per kx row (0..255). All rows: per-segment counts (LDS hist
// -> global atomics). Rows 0..128 additionally emit the boundary table: per
// (kx, bin) the <=2 contiguous ky-runs (radius monotone for ky 0..128,
// mirrored above), as prefix-lookup indices; 256 = zero sentinel slot.
__global__ __launch_bounds__(256) void k_prep(const int* __restrict__ seg,
                                              int4* __restrict__ tbl,
                                              int* __restrict__ cnt) {
    __shared__ int lo1[NSEG], hi1[NSEG], lo2[NSEG], hi2[NSEG], lc[NSEG];
    const int kx = blockIdx.x, ky = threadIdx.x;
    if (ky < NSEG) { lo1[ky] = 300; hi1[ky] = -1; lo2[ky] = 300; hi2[ky] = -1; lc[ky] = 0; }
    __syncthreads();
    const int s = seg[kx * 256 + ky];
    atomicAdd(&lc[s], 1);
    if (kx <= 128) {
        if (ky <= 128) { atomicMin(&lo1[s], ky); atomicMax(&hi1[s], ky); }
        else           { atomicMin(&lo2[s], ky); atomicMax(&hi2[s], ky); }
    }
    __syncthreads();
    if (ky < NSEG && lc[ky] > 0) atomicAdd(&cnt[ky], lc[ky]);
    if (kx <= 128 && ky >= 1 && ky <= 64) {
        int4 t;
        if (hi1[ky] < 0) { t.x = 256; t.y = 256; }
        else             { t.x = (lo1[ky] > 0) ? lo1[ky] - 1 : 256; t.y = hi1[ky]; }
        if (hi2[ky] < 0) { t.z = 256; t.w = 256; }
        else             { t.z = lo2[ky] - 1; t.w = hi2[ky]; }
        tbl[kx * 64 + (ky - 1)] = t;
    }
}

extern "C" void kernel_launch(void* const* d_in, const int* in_sizes, int n_in,
                              void* d_out, int out_size, void* d_ws, size_t ws_size,
                              hipStream_t stream) {
    const float* pred      = (const float*)d_in[0];
    const float* mean_cl   = (const float*)d_in[1];
    const float* weighting = (const float*)d_in[2];
    const int*   seg       = (const int*)d_in[3];
    float* out = (float*)d_out;

    const int B = in_sizes[0] / 65536;

    // ws: [cnt 66 i32, pad to 256B][boundary table 129*64 int4]
    int*  cnt = (int*)d_ws;
    int4* tbl = (int4*)((char*)d_ws + 256);

    const double rad = (5.0 * 60.0 / 256.0) * M_PI / 180.0;
    const float cscale = (float)(rad * rad / (65536.0 * 1e12)); // rad^2/N^2/TSZ^2
    const float invB64 = (float)(1.0 / ((double)B * 64.0));

    hipMemsetAsync(d_out, 0, sizeof(float), stream);
    hipMemsetAsync(cnt, 0, NSEG * sizeof(int), stream);
    k_prep<<<256, 256, 0, stream>>>(seg, tbl, cnt);
    k_fused<<<B, 1024, 0, stream>>>(pred, tbl, cnt, mean_cl, weighting,
                                    out, cscale, invB64);
}

// Round 12
// 122.404 us; speedup vs baseline: 5.0836x; 1.1733x over previous
//
#include <hip/hip_runtime.h>
#include <hip/hip_fp16.h>
#include <math.h>

#define NSEG 66                 // segments 0..65; valid bins 1..64
typedef unsigned uv2 __attribute__((ext_vector_type(2)));
typedef unsigned h2u;           // half2 bit pattern: lo = re, hi = im

__device__ __forceinline__ int brev6(int l) {
    return ((l&1)<<5)|((l&2)<<3)|((l&4)<<1)|((l&8)>>1)|((l&16)>>3)|((l&32)>>5);
}
__device__ __forceinline__ h2u f2h(float a, float b) {
    __half2 h = __floats2half2_rn(a, b); return *reinterpret_cast<unsigned*>(&h);
}

// ---------------- packed f16 primitives (VOP3P, one VGPR per complex) ----------------
__device__ __forceinline__ h2u pkh_fma(h2u a, h2u b, h2u c) {   // a*b + c (per half)
    h2u d; asm("v_pk_fma_f16 %0, %1, %2, %3" : "=v"(d) : "v"(a), "v"(b), "v"(c));
    return d;
}
__device__ __forceinline__ h2u pkh_mul(h2u a, h2u b) {
    h2u d; asm("v_pk_mul_f16 %0, %1, %2" : "=v"(d) : "v"(a), "v"(b));
    return d;
}
__device__ __forceinline__ h2u pkh_add(h2u a, h2u b) {
    h2u d; asm("v_pk_add_f16 %0, %1, %2" : "=v"(d) : "v"(a), "v"(b));
    return d;
}
__device__ __forceinline__ h2u pkh_sub(h2u a, h2u b) {
    h2u d; asm("v_pk_add_f16 %0, %1, %2 neg_lo:[0,1] neg_hi:[0,1]" : "=v"(d) : "v"(a), "v"(b));
    return d;
}
__device__ __forceinline__ h2u pkh_addmi(h2u a, h2u b) {  // a - i*b = (a.lo+b.hi, a.hi-b.lo)
    h2u d; asm("v_pk_add_f16 %0, %1, %2 op_sel:[0,1] op_sel_hi:[1,0] neg_hi:[0,1]"
               : "=v"(d) : "v"(a), "v"(b));
    return d;
}
__device__ __forceinline__ h2u pkh_addpi(h2u a, h2u b) {  // a + i*b = (a.lo-b.hi, a.hi+b.lo)
    h2u d; asm("v_pk_add_f16 %0, %1, %2 op_sel:[0,1] op_sel_hi:[1,0] neg_lo:[0,1]"
               : "=v"(d) : "v"(a), "v"(b));
    return d;
}
// complex mul: z=(x,y), ta=(c,s), tb=(-s,s) -> (xc - ys, xs + yc)
__device__ __forceinline__ h2u cmulh(h2u z, h2u ta, h2u tb) {
    h2u p, r;
    asm("v_pk_mul_f16 %0, %1, %2 op_sel:[0,0] op_sel_hi:[1,0]" : "=v"(p) : "v"(z), "v"(ta));
    asm("v_pk_fma_f16 %0, %1, %2, %3 op_sel:[1,0,0] op_sel_hi:[0,1,1]"
        : "=v"(r) : "v"(z), "v"(tb), "v"(p));
    return r;
}
// swapped-src0 variants for the Hermitian unpack
__device__ __forceinline__ h2u pkh_mul_sw0(h2u a, h2u b) {  // (a.hi*b.lo, a.lo*b.hi)
    h2u d; asm("v_pk_mul_f16 %0, %1, %2 op_sel:[1,0] op_sel_hi:[0,1]" : "=v"(d) : "v"(a), "v"(b));
    return d;
}
__device__ __forceinline__ h2u pkh_fma_sw0(h2u a, h2u b, h2u c) { // (a.hi*b.lo+c.lo, a.lo*b.hi+c.hi)
    h2u d; asm("v_pk_fma_f16 %0, %1, %2, %3 op_sel:[1,0,0] op_sel_hi:[0,1,1]"
               : "=v"(d) : "v"(a), "v"(b), "v"(c));
    return d;
}

#define C_PP 0x38003800u    // half2 ( 0.5,  0.5)
#define C_PM 0xB8003800u    // half2 ( 0.5, -0.5)

// Per-lane constants (all f16-packed, one VGPR each).
struct XTH {
    h2u ta32, tb32, sg32;
    h2u ta16, tb16, sg16;
    h2u ta8,  tb8,  sg8;
    h2u ta4,  tb4,  sg4;
    h2u ta2,  tb2,  sg2;
    h2u sg1;
    h2u wa1, wb1, wa2, wb2, wa3, wb3;   // W256^{brev(L)},^2,^3
    int pl;                             // Hermitian partner lane
};

// ---- cross-lane exchange + packed butterfly ----
__device__ __forceinline__ h2u bflyh_pl32(h2u z, h2u sg, h2u ta, h2u tb) {
#if __has_builtin(__builtin_amdgcn_permlane32_swap)
    uv2 r = __builtin_amdgcn_permlane32_swap(z, z, false, false);
    h2u u = pkh_fma(r[1], sg, r[0]);
#else
    h2u c = __float_as_uint(__shfl_xor(__uint_as_float(z), 32));
    h2u u = pkh_fma(z, sg, c);
#endif
    return cmulh(u, ta, tb);
}
__device__ __forceinline__ h2u bflyh_pl16(h2u z, h2u sg, h2u ta, h2u tb) {
#if __has_builtin(__builtin_amdgcn_permlane16_swap)
    uv2 r = __builtin_amdgcn_permlane16_swap(z, z, false, false);
    h2u u = pkh_fma(r[1], sg, r[0]);
#else
    h2u c = __float_as_uint(__shfl_xor(__uint_as_float(z), 16));
    h2u u = pkh_fma(z, sg, c);
#endif
    return cmulh(u, ta, tb);
}
template<int CTRL>
__device__ __forceinline__ h2u dppx(h2u x) {
#if __has_builtin(__builtin_amdgcn_update_dpp)
    return (h2u)__builtin_amdgcn_update_dpp((int)x, (int)x, CTRL, 0xF, 0xF, false);
#else
    const int d = (CTRL == 0x128) ? 8 : (CTRL == 0x4E ? 2 : 1);
    return __float_as_uint(__shfl_xor(__uint_as_float(x), d));
#endif
}
template<int CTRL>
__device__ __forceinline__ h2u bflyh_dpp(h2u z, h2u sg, h2u ta, h2u tb) {
    return cmulh(pkh_fma(z, sg, dppx<CTRL>(z)), ta, tb);
}
__device__ __forceinline__ h2u bflyh1(h2u z, h2u sg) {   // d=1, tw==1
    return pkh_fma(z, sg, dppx<0xB1>(z));
}
__device__ __forceinline__ h2u bflyh_ds4(h2u z, h2u sg, h2u ta, h2u tb) {
    h2u c = (h2u)__builtin_amdgcn_ds_swizzle((int)z, 0x101F);   // xor-4
    return cmulh(pkh_fma(z, sg, c), ta, tb);
}

// 64-lane inclusive prefix sum on the VALU (DPP scan), f32.
__device__ __forceinline__ float dpp_scan64(float x, int L) {
#if __has_builtin(__builtin_amdgcn_update_dpp)
    #define UPD(ctrl, rmask) __int_as_float(__builtin_amdgcn_update_dpp( \
        0, __float_as_int(x), ctrl, rmask, 0xF, false))
    x += UPD(0x111, 0xF);   // row_shr:1
    x += UPD(0x112, 0xF);   // row_shr:2
    x += UPD(0x114, 0xF);   // row_shr:4
    x += UPD(0x118, 0xF);   // row_shr:8
    x += UPD(0x142, 0xA);   // row_bcast:15 -> rows 1,3
    x += UPD(0x143, 0xC);   // row_bcast:31 -> rows 2,3
    #undef UPD
    return x;
#else
    #pragma unroll
    for (int off = 1; off < 64; off <<= 1) {
        const float yv = __shfl_up(x, off);
        if (L >= off) x += yv;
    }
    return x;
#endif
}

// Four independent 64-pt FFTs in f16; result at lane L is G[brev6(L)].
__device__ __forceinline__ void fft64x4h(h2u z[4], const XTH& T) {
    #pragma unroll
    for (int a = 0; a < 4; ++a) {
        z[a] = bflyh_pl32(z[a], T.sg32, T.ta32, T.tb32);
        z[a] = bflyh_pl16(z[a], T.sg16, T.ta16, T.tb16);
        z[a] = bflyh_dpp<0x128>(z[a], T.sg8, T.ta8, T.tb8);
        z[a] = bflyh_ds4(z[a], T.sg4, T.ta4, T.tb4);
        z[a] = bflyh_dpp<0x4E>(z[a], T.sg2, T.ta2, T.tb2);
        z[a] = bflyh1(z[a], T.sg1);
    }
}
// Twiddle by W256^{a*brev(L)} then in-lane DFT4: X[q] = F[brev6(L) + 64q].
__device__ __forceinline__ void twdft4h(const h2u z[4], const XTH& T, h2u X[4]) {
    h2u g0 = z[0];
    h2u g1 = cmulh(z[1], T.wa1, T.wb1);
    h2u g2 = cmulh(z[2], T.wa2, T.wb2);
    h2u g3 = cmulh(z[3], T.wa3, T.wb3);
    h2u b0 = pkh_add(g0, g2), b1 = pkh_sub(g0, g2);
    h2u b2 = pkh_add(g1, g3), b3 = pkh_sub(g1, g3);
    X[0] = pkh_add(b0, b2);
    X[2] = pkh_sub(b0, b2);
    X[1] = pkh_addmi(b1, b3);   // b1 - i*b3
    X[3] = pkh_addpi(b1, b3);   // b1 + i*b3
}

// One 1024-thread workgroup per image. f16 row-pair FFTs -> half2 LDS tile
// [kx][y^(kx&28)] -> f16 column FFTs -> f32 |F|^2 via fma_mix -> scan binning -> loss.
__global__ __launch_bounds__(1024)
void k_fused(const float* __restrict__ pred, const int4* __restrict__ tbl,
             const int* __restrict__ cnt, const float* __restrict__ mean_cl,
             const float* __restrict__ weighting, float* __restrict__ out,
             float cscale, float invB64) {
    __shared__ __align__(16) unsigned tile[129 * 256];   // half2 as u32, 132096 B
    __shared__ __align__(16) float pbuf[16][260];        // per-wave scan buffer
    const int tid = threadIdx.x, w = tid >> 6, L = tid & 63;
    const int rL = brev6(L);
    const float PI2 = 6.283185307179586f;

    XTH T;
    {
        auto stw = [&](int d, h2u& ta, h2u& tb, h2u& sg) {
            const float s = (L & d) ? -1.f : 1.f;
            const int e = (L & d) ? (L & (d-1)) * (32/d) : 0;
            float ss, cc; __sincosf(-PI2 * (float)e / 64.f, &ss, &cc);
            ta = f2h(cc, ss); tb = f2h(-ss, ss); sg = f2h(s, s);
        };
        stw(32, T.ta32, T.tb32, T.sg32);
        stw(16, T.ta16, T.tb16, T.sg16);
        stw( 8, T.ta8,  T.tb8,  T.sg8);
        stw( 4, T.ta4,  T.tb4,  T.sg4);
        stw( 2, T.ta2,  T.tb2,  T.sg2);
        const float s1 = (L & 1) ? -1.f : 1.f;
        T.sg1 = f2h(s1, s1);
        float sg, cg;
        __sincosf(-PI2 * (float)rL / 256.f, &sg, &cg);
        const float w2x = cg*cg - sg*sg, w2y = 2.f*cg*sg;
        const float w3x = w2x*cg - w2y*sg, w3y = w2x*sg + w2y*cg;
        T.wa1 = f2h(cg, sg);   T.wb1 = f2h(-sg, sg);
        T.wa2 = f2h(w2x, w2y); T.wb2 = f2h(-w2y, w2y);
        T.wa3 = f2h(w3x, w3y); T.wb3 = f2h(-w3y, w3y);
        T.pl = brev6((64 - rL) & 63);
    }

    // ---------------- row phase: 8 row-pairs per wave ----------------
    const float* base = pred + (size_t)blockIdx.x * 65536;
    const int sw = rL & 28;
    #pragma unroll 2
    for (int t = 0; t < 8; ++t) {
        const int y = 16*w + 2*t;
        const float4 ra = *(const float4*)(base + (size_t)y*256 + 4*L);
        const float4 rb = *(const float4*)(base + (size_t)(y+1)*256 + 4*L);
        h2u z[4] = { f2h(ra.x, rb.x), f2h(ra.y, rb.y), f2h(ra.z, rb.z), f2h(ra.w, rb.w) };
        fft64x4h(z, T);                 // packed-FFT Z at kx=brev(L)+64q
        h2u X[4]; twdft4h(z, T, X);
        // Hermitian unpack partners: conj(Z[256-kx]) — one 32-bit shuffle each
        h2u q0 = __float_as_uint(__shfl(__uint_as_float(X[3]), T.pl));
        h2u q1 = __float_as_uint(__shfl(__uint_as_float(X[2]), T.pl));
        if (L == 0) { q0 = X[0]; q1 = X[3]; }   // kx=0 and kx=64 fixes
        const int yi = y ^ sw;                   // y even, sw low2=0 -> +1 ok
        {   // kx = rL:  F_y = 0.5(A+conj(q)),  F_{y+1} = -0.5i(A-conj(q))
            const h2u F = pkh_fma(q0, C_PM, pkh_mul(X[0], C_PP));
            const h2u G = pkh_fma_sw0(q0, C_PP, pkh_mul_sw0(X[0], C_PM));
            uint2 pk; pk.x = F; pk.y = G;
            *(uint2*)&tile[rL*256 + yi] = pk;
        }
        {   // kx = 64 + rL  (same swizzle: (64+rL)&28 == rL&28)
            const h2u F = pkh_fma(q1, C_PM, pkh_mul(X[1], C_PP));
            const h2u G = pkh_fma_sw0(q1, C_PP, pkh_mul_sw0(X[1], C_PM));
            uint2 pk; pk.x = F; pk.y = G;
            *(uint2*)&tile[(64+rL)*256 + yi] = pk;
        }
        if (L == 0) {   // kx = 128: Z[128] self-conjugate -> rows get (Re,0),(Im,0)
            uint2 pk; pk.x = X[2] & 0xFFFFu; pk.y = X[2] >> 16;
            *(uint2*)&tile[128*256 + y] = pk;
        }
    }
    __syncthreads();

    // ---------------- column phase: kx = w + 16t ----------------
    float acc = 0.f;                   // lane accumulates bin (L+1)
    float* pb = pbuf[w];
    const float zf = 0.0f;
    if (L == 0) pb[256] = 0.f;         // sentinel (float4 stores cover 0..255 only)
    #pragma unroll 2
    for (int kx = w; kx <= 128; kx += 16) {
        const int cs = kx & 28;
        const int4 tb = tbl[kx*64 + L];  // <=2 ky-runs as prefix indices (early issue)
        const uint4 uu = *(const uint4*)&tile[kx*256 + ((4*L) ^ cs)];
        h2u z[4] = { uu.x, uu.y, uu.z, uu.w };   // x[4L+a] directly (f16)
        fft64x4h(z, T);
        h2u X[4]; twdft4h(z, T, X);    // X[q] = F[ky = brev(L) + 64q]
        float p0, p1, p2, p3;          // |F|^2 in f32 straight from f16 halves
        #define POW2(P, XS)                                                     \
            asm("v_fma_mix_f32 %0, %2, %2, %1 op_sel:[0,0,0] op_sel_hi:[1,1,0]" \
                : "=v"(P) : "v"(zf), "v"(XS));                                  \
            asm("v_fma_mix_f32 %0, %1, %1, %0 op_sel:[1,1,0] op_sel_hi:[1,1,0]" \
                : "+v"(P) : "v"(XS));
        POW2(p0, X[0]) POW2(p1, X[1]) POW2(p2, X[2]) POW2(p3, X[3])
        #undef POW2
        pb[rL]       = p0;             // natural-order scatter
        pb[rL + 64]  = p1;
        pb[rL + 128] = p2;
        pb[rL + 192] = p3;
        const float4 pv = ((const float4*)pb)[L];
        const float s0 = pv.x, s1 = s0+pv.y, s2 = s1+pv.z, s3 = s2+pv.w;
        const float x = dpp_scan64(s3, L);          // inclusive scan of lane totals
        const float ex = x - s3;       // exclusive prefix of the lane's 4-group
        ((float4*)pb)[L] = make_float4(ex+s0, ex+s1, ex+s2, ex+s3);
        const float csum = pb[tb.y] - pb[tb.x] + pb[tb.w] - pb[tb.z];
        const float symw = (kx == 0 || kx == 128) ? 1.f : 2.f;
        acc = fmaf(symw, csum, acc);
    }
    __syncthreads();

    // ---------------- reduce 16 waves, per-image loss ----------------
    float* bins = (float*)tile;        // tile dead now
    bins[w*64 + L] = acc;
    __syncthreads();
    if (tid < 64) {
        float tot = 0.f;
        #pragma unroll
        for (int ww = 0; ww < 16; ++ww) tot += bins[ww*64 + tid];
        const int c = cnt[tid + 1];
        const float inv = (c > 0) ? 1.0f / (float)c : 0.0f;
        const float v = tot * cscale * inv;
        const float d = logf(v + 1e-12f) - logf(mean_cl[tid] + 1e-12f);
        float l = weighting[tid] * d * d;
        #pragma unroll
        for (int o = 32; o; o >>= 1) l += __shfl_down(l, o);
        if (tid == 0) atomicAdd(out, l * invB64);
    }
}

// Prep: one block per kx row (0..255). All rows: per-segment counts. Rows
// 0..128 additionally emit the boundary table (<=2 contiguous ky-runs as
// prefix-lookup indices; 256 = zero sentinel slot).
__global__ __launch_bounds__(256) void k_prep(const int* __restrict__ seg,
                                              int4* __restrict__ tbl,
                                              int* __restrict__ cnt) {
    __shared__ int lo1[NSEG], hi1[NSEG], lo2[NSEG], hi2[NSEG], lc[NSEG];
    const int kx = blockIdx.x, ky = threadIdx.x;
    if (ky < NSEG) { lo1[ky] = 300; hi1[ky] = -1; lo2[ky] = 300; hi2[ky] = -1; lc[ky] = 0; }
    __syncthreads();
    const int s = seg[kx * 256 + ky];
    atomicAdd(&lc[s], 1);
    if (kx <= 128) {
        if (ky <= 128) { atomicMin(&lo1[s], ky); atomicMax(&hi1[s], ky); }
        else           { atomicMin(&lo2[s], ky); atomicMax(&hi2[s], ky); }
    }
    __syncthreads();
    if (ky < NSEG && lc[ky] > 0) atomicAdd(&cnt[ky], lc[ky]);
    if (kx <= 128 && ky >= 1 && ky <= 64) {
        int4 t;
        if (hi1[ky] < 0) { t.x = 256; t.y = 256; }
        else             { t.x = (lo1[ky] > 0) ? lo1[ky] - 1 : 256; t.y = hi1[ky]; }
        if (hi2[ky] < 0) { t.z = 256; t.w = 256; }
        else             { t.z = lo2[ky] - 1; t.w = hi2[ky]; }
        tbl[kx * 64 + (ky - 1)] = t;
    }
}

extern "C" void kernel_launch(void* const* d_in, const int* in_sizes, int n_in,
                              void* d_out, int out_size, void* d_ws, size_t ws_size,
                              hipStream_t stream) {
    const float* pred      = (const float*)d_in[0];
    const float* mean_cl   = (const float*)d_in[1];
    const float* weighting = (const float*)d_in[2];
    const int*   seg       = (const int*)d_in[3];
    float* out = (float*)d_out;

    const int B = in_sizes[0] / 65536;

    // ws: [cnt 66 i32, pad to 256B][boundary table 129*64 int4]
    int*  cnt = (int*)d_ws;
    int4* tbl = (int4*)((char*)d_ws + 256);

    const double rad = (5.0 * 60.0 / 256.0) * M_PI / 180.0;
    const float cscale = (float)(rad * rad / (65536.0 * 1e12)); // rad^2/N^2/TSZ^2
    const float invB64 = (float)(1.0 / ((double)B * 64.0));

    hipMemsetAsync(d_out, 0, sizeof(float), stream);
    hipMemsetAsync(cnt, 0, NSEG * sizeof(int), stream);
    k_prep<<<256, 256, 0, stream>>>(seg, tbl, cnt);
    k_fused<<<B, 1024, 0, stream>>>(pred, tbl, cnt, mean_cl, weighting,
                                    out, cscale, invB64);
}